// Round 10
// baseline (678.907 us; speedup 1.0000x reference)
//
#include <hip/hip_runtime.h>

#define N_NODES 50000
#define N_EDGES 800000
#define DIM 128
#define NLAYERS 4
#define BN_EPS 1e-5f
#define SCAN_BLOCKS 196   // ceil(N_NODES/256)
#define WSTRIDE 136       // 128 + 8 bf16 pad (LDS bank decorrelation)

typedef __attribute__((ext_vector_type(8))) short short8;
typedef __attribute__((ext_vector_type(4))) float f32x4;

__device__ __forceinline__ float bf2f(unsigned short u){
    union { unsigned int i; float f; } x; x.i = ((unsigned int)u) << 16; return x.f;
}
__device__ __forceinline__ unsigned short f2bf(float f){
    union { float f; unsigned int i; } x; x.f = f;
    unsigned int lsb = (x.i >> 16) & 1u;
    unsigned int r = x.i + 0x7fffu + lsb;
    return (unsigned short)(r >> 16);
}

// ---------------- prep kernels ----------------

__global__ __launch_bounds__(256) void k_zero(int* __restrict__ p, int n){
    int i = blockIdx.x * 256 + threadIdx.x;
    if (i < n) p[i] = 0;
}

__global__ __launch_bounds__(256) void k_count(const int* __restrict__ dst,
                                               int* __restrict__ degcnt){
    int e = blockIdx.x * 256 + threadIdx.x;
    if (e < N_EDGES) atomicAdd(&degcnt[dst[e]], 1);
}

// phase 1 + dis: per-block exclusive scan of degcnt; also dis = rsqrt(deg+1)
__global__ __launch_bounds__(256) void k_scan1(const int* __restrict__ degcnt,
                                               int* __restrict__ rowptr,
                                               int* __restrict__ bsum,
                                               float* __restrict__ dis){
    __shared__ int tmp[256];
    int t = threadIdx.x;
    int i = blockIdx.x * 256 + t;
    int v = (i < N_NODES) ? degcnt[i] : 0;
    if (i < N_NODES) dis[i] = rsqrtf((float)v + 1.0f);
    tmp[t] = v;
    __syncthreads();
    #pragma unroll
    for (int off = 1; off < 256; off <<= 1){
        int u = (t >= off) ? tmp[t - off] : 0;
        __syncthreads();
        tmp[t] += u;
        __syncthreads();
    }
    if (i < N_NODES) rowptr[i] = tmp[t] - v;
    if (t == 255) bsum[blockIdx.x] = tmp[255];
}

__global__ __launch_bounds__(256) void k_scan2(int* __restrict__ bsum){
    __shared__ int tmp[256];
    int t = threadIdx.x;
    int v = (t < SCAN_BLOCKS) ? bsum[t] : 0;
    tmp[t] = v;
    __syncthreads();
    #pragma unroll
    for (int off = 1; off < 256; off <<= 1){
        int u = (t >= off) ? tmp[t - off] : 0;
        __syncthreads();
        tmp[t] += u;
        __syncthreads();
    }
    if (t < SCAN_BLOCKS) bsum[t] = tmp[t] - v;
}

__global__ __launch_bounds__(256) void k_scan3(const int* __restrict__ bsum,
                                               int* __restrict__ rowptr,
                                               int* __restrict__ wptr){
    int i = blockIdx.x * 256 + threadIdx.x;
    if (i < N_NODES){
        int r = rowptr[i] + bsum[blockIdx.x];
        rowptr[i] = r; wptr[i] = r;
    }
    if (i == 0) rowptr[N_NODES] = N_EDGES;
}

__global__ __launch_bounds__(256) void k_fill(const int* __restrict__ src,
                                              const int* __restrict__ dst,
                                              const float* __restrict__ dis,
                                              int* __restrict__ wptr,
                                              int2* __restrict__ epair){
    int e = blockIdx.x * 256 + threadIdx.x;
    if (e < N_EDGES){
        int s = src[e], d = dst[e];
        float w = dis[s] * dis[d];
        int p = atomicAdd(&wptr[d], 1);
        int2 pr; pr.x = s; pr.y = __float_as_int(w);
        epair[p] = pr;
    }
}

// W' = diag(sc)*W; write W'^T (c-major) bf16 hi/lo. Block 64 computes
// bias2[c] = sum_k sh[k]*W[k][c].
template<bool HAS>
__global__ __launch_bounds__(256) void k_wprep(const float* __restrict__ W,
                                               const float* __restrict__ scsh,
                                               unsigned short* __restrict__ wthi,
                                               unsigned short* __restrict__ wtlo,
                                               float* __restrict__ bias2){
    int tid = threadIdx.x;
    if (blockIdx.x < 64){
        int idx = blockIdx.x * 256 + tid;        // 0..16383
        int c = idx >> 7, k = idx & 127;
        float v = W[k*DIM + c];
        if (HAS) v *= scsh[k];
        unsigned short hi = f2bf(v);
        float lo = v - bf2f(hi);
        wthi[c*DIM + k] = hi;
        wtlo[c*DIM + k] = f2bf(lo);
    } else {
        __shared__ float part[256];
        int c = tid >> 1, half = tid & 1;
        float acc = 0.f;
        if (HAS){
            int k0 = half * 64;
            #pragma unroll 4
            for (int k = k0; k < k0 + 64; k++)
                acc = fmaf(scsh[DIM + k], W[k*DIM + c], acc);
        }
        part[tid] = acc;
        __syncthreads();
        if (half == 0) bias2[c] = part[2*c] + part[2*c + 1];
    }
}

// ---------------- per-layer kernels ----------------
// Grouped feature layout: t[g][node][32 cols], g = col>>5 (3.2MB/slice).

// MFMA GEMM: h = z @ W' + bias2.  MODE 0: z = x fp32 std layout. MODE 1: z
// grouped bf16. W'^T hi/lo bf16 staged in LDS, h grouped bf16.
// 64 rows/block, 4 waves; wave = 16 rows x 128 cols = 8 mfma 16x16x32, K=128.
template<int MODE>
__global__ __launch_bounds__(256) void k_gemm(const void* __restrict__ zraw,
                                              const unsigned short* __restrict__ wthi,
                                              const unsigned short* __restrict__ wtlo,
                                              const float* __restrict__ bias2,
                                              unsigned short* __restrict__ hb){
    __shared__ short whi[DIM * WSTRIDE];       // 34816 B
    __shared__ short wlo[DIM * WSTRIDE];       // 34816 B
    int tid = threadIdx.x;

    {
        const uint4* gh = (const uint4*)wthi;
        const uint4* gl = (const uint4*)wtlo;
        #pragma unroll
        for (int it = 0; it < 8; it++){
            int ch = tid + 256*it;             // 0..2047
            int c = ch >> 4, k8 = ch & 15;
            int off = c*WSTRIDE + k8*8;
            *(uint4*)&whi[off] = gh[ch];
            *(uint4*)&wlo[off] = gl[ch];
        }
    }
    __syncthreads();

    int lane = tid & 63;
    int wv   = tid >> 6;
    int m = lane & 15;
    int q = lane >> 4;
    int row0 = blockIdx.x * 64 + wv * 16;
    int arow = row0 + m;
    bool avalid = arow < N_NODES;

    f32x4 acc[8];
    #pragma unroll
    for (int t = 0; t < 8; t++) acc[t] = (f32x4){0.f, 0.f, 0.f, 0.f};

    #pragma unroll
    for (int g = 0; g < 4; g++){               // k-step = feature group
        short8 a = {0,0,0,0,0,0,0,0};
        if (avalid){
            if (MODE == 0){
                const float* xp = (const float*)zraw + (size_t)arow*DIM + g*32 + q*8;
                float4 v0 = *(const float4*)xp;
                float4 v1 = *(const float4*)(xp + 4);
                a[0] = (short)f2bf(v0.x); a[1] = (short)f2bf(v0.y);
                a[2] = (short)f2bf(v0.z); a[3] = (short)f2bf(v0.w);
                a[4] = (short)f2bf(v1.x); a[5] = (short)f2bf(v1.y);
                a[6] = (short)f2bf(v1.z); a[7] = (short)f2bf(v1.w);
            } else {
                a = *(const short8*)((const unsigned short*)zraw
                      + (size_t)g*N_NODES*32 + (size_t)arow*32 + q*8);
            }
        }
        #pragma unroll
        for (int t = 0; t < 8; t++){
            int col = t*16 + m;
            int off = col*WSTRIDE + g*32 + q*8;
            short8 bh = *(const short8*)&whi[off];
            short8 bl = *(const short8*)&wlo[off];
            acc[t] = __builtin_amdgcn_mfma_f32_16x16x32_bf16(a, bh, acc[t], 0, 0, 0);
            acc[t] = __builtin_amdgcn_mfma_f32_16x16x32_bf16(a, bl, acc[t], 0, 0, 0);
        }
    }

    #pragma unroll
    for (int t = 0; t < 8; t++){
        int colg = t*16 + m;
        float bz = bias2[colg];
        size_t base = (size_t)(t >> 1)*N_NODES*32 + (t & 1)*16 + m;
        #pragma unroll
        for (int r = 0; r < 4; r++){
            int row = row0 + q*4 + r;
            if (row < N_NODES)
                hb[base + (size_t)row*32] = f2bf(acc[t][r] + bz);
        }
    }
}

// CSR aggregation + bias + ReLU + per-column stats, feature-group partitioned.
// group = blockIdx&3. Lane loads uint2 (4 bf16 cols): 8 lanes/edge, 8 edges
// per wave-gather, 16-edge main loop (2 gathers in flight).
__global__ __launch_bounds__(256) void k_agg(const unsigned short* __restrict__ h,
                                             const int* __restrict__ rowptr,
                                             const int2* __restrict__ epair,
                                             const float* __restrict__ dis,
                                             const float* __restrict__ bias,
                                             unsigned short* __restrict__ out,
                                             float* __restrict__ stats){
    int lane = threadIdx.x & 63;
    int w    = threadIdx.x >> 6;
    int g    = blockIdx.x & 3;
    int sub  = lane >> 3;                      // edge slot 0..7
    int cp   = lane & 7;                       // uint2 (4 cols) within group
    const uint2* hg = (const uint2*)(h + (size_t)g * N_NODES * 32);
    ushort4* og = (ushort4*)(out + (size_t)g * N_NODES * 32);
    float b[4];
    #pragma unroll
    for (int j = 0; j < 4; j++) b[j] = bias[g*32 + 4*cp + j];
    float s[4] = {0.f,0.f,0.f,0.f}, qq[4] = {0.f,0.f,0.f,0.f};
    int bg = blockIdx.x >> 2;
    int nstride = (gridDim.x >> 2) * 4;

    for (int node = bg*4 + w; node < N_NODES; node += nstride){
        float di = dis[node];
        int e0 = rowptr[node], e1 = rowptr[node + 1];
        float pa[4] = {0.f,0.f,0.f,0.f}, pb[4] = {0.f,0.f,0.f,0.f};
        if (sub == 0){
            uint2 hv = hg[node*8 + cp];
            float dii = di * di;
            pa[0] = bf2f((unsigned short)(hv.x & 0xffff)) * dii;
            pa[1] = bf2f((unsigned short)(hv.x >> 16))    * dii;
            pa[2] = bf2f((unsigned short)(hv.y & 0xffff)) * dii;
            pa[3] = bf2f((unsigned short)(hv.y >> 16))    * dii;
        }
        int e = e0;
        for (; e + 16 <= e1; e += 16){
            int2 P0 = epair[e + sub];
            int2 P1 = epair[e + 8 + sub];
            uint2 X0 = hg[P0.x*8 + cp];
            uint2 X1 = hg[P1.x*8 + cp];
            float w0 = __int_as_float(P0.y), w1 = __int_as_float(P1.y);
            pa[0] = fmaf(bf2f((unsigned short)(X0.x & 0xffff)), w0, pa[0]);
            pa[1] = fmaf(bf2f((unsigned short)(X0.x >> 16)),    w0, pa[1]);
            pa[2] = fmaf(bf2f((unsigned short)(X0.y & 0xffff)), w0, pa[2]);
            pa[3] = fmaf(bf2f((unsigned short)(X0.y >> 16)),    w0, pa[3]);
            pb[0] = fmaf(bf2f((unsigned short)(X1.x & 0xffff)), w1, pb[0]);
            pb[1] = fmaf(bf2f((unsigned short)(X1.x >> 16)),    w1, pb[1]);
            pb[2] = fmaf(bf2f((unsigned short)(X1.y & 0xffff)), w1, pb[2]);
            pb[3] = fmaf(bf2f((unsigned short)(X1.y >> 16)),    w1, pb[3]);
        }
        if (e + 8 <= e1){
            int2 P0 = epair[e + sub];
            uint2 X0 = hg[P0.x*8 + cp];
            float w0 = __int_as_float(P0.y);
            pa[0] = fmaf(bf2f((unsigned short)(X0.x & 0xffff)), w0, pa[0]);
            pa[1] = fmaf(bf2f((unsigned short)(X0.x >> 16)),    w0, pa[1]);
            pa[2] = fmaf(bf2f((unsigned short)(X0.y & 0xffff)), w0, pa[2]);
            pa[3] = fmaf(bf2f((unsigned short)(X0.y >> 16)),    w0, pa[3]);
            e += 8;
        }
        if (e < e1){
            int ide = e + sub;
            int2 pr = (ide < e1) ? epair[ide] : make_int2(0, 0);
            uint2 xv = hg[pr.x*8 + cp];
            float we = __int_as_float(pr.y);   // 0.0f for masked lanes
            pb[0] = fmaf(bf2f((unsigned short)(xv.x & 0xffff)), we, pb[0]);
            pb[1] = fmaf(bf2f((unsigned short)(xv.x >> 16)),    we, pb[1]);
            pb[2] = fmaf(bf2f((unsigned short)(xv.y & 0xffff)), we, pb[2]);
            pb[3] = fmaf(bf2f((unsigned short)(xv.y >> 16)),    we, pb[3]);
        }
        float r[4];
        #pragma unroll
        for (int j = 0; j < 4; j++){
            r[j] = pa[j] + pb[j];
            r[j] += __shfl_xor(r[j], 8);
            r[j] += __shfl_xor(r[j], 16);
            r[j] += __shfl_xor(r[j], 32);
        }
        if (sub == 0){
            float a0 = fmaxf(r[0] + b[0], 0.f);
            float a1 = fmaxf(r[1] + b[1], 0.f);
            float a2 = fmaxf(r[2] + b[2], 0.f);
            float a3 = fmaxf(r[3] + b[3], 0.f);
            ushort4 ov;
            ov.x = f2bf(a0); ov.y = f2bf(a1); ov.z = f2bf(a2); ov.w = f2bf(a3);
            og[node*8 + cp] = ov;
            s[0] += a0; s[1] += a1; s[2] += a2; s[3] += a3;
            qq[0] += a0*a0; qq[1] += a1*a1; qq[2] += a2*a2; qq[3] += a3*a3;
        }
    }

    __shared__ float red[4][8][8];
    if (sub == 0){
        #pragma unroll
        for (int j = 0; j < 4; j++){
            red[w][cp][j]     = s[j];
            red[w][cp][4 + j] = qq[j];
        }
    }
    __syncthreads();
    if (w == 0 && sub == 0){
        #pragma unroll
        for (int ww = 1; ww < 4; ww++)
            #pragma unroll
            for (int j = 0; j < 4; j++){
                s[j]  += red[ww][cp][j];
                qq[j] += red[ww][cp][4 + j];
            }
        int c = g*32 + 4*cp;
        #pragma unroll
        for (int j = 0; j < 4; j++){
            atomicAdd(&stats[c + j],       s[j]);
            atomicAdd(&stats[DIM + c + j], qq[j]);
        }
    }
}

// stats -> per-column scale/shift:  sc = rstd*gamma, sh = beta - mu*sc
__global__ void k_bnstat(const float* __restrict__ stats,
                         const float* __restrict__ gamma,
                         const float* __restrict__ beta,
                         float* __restrict__ scsh){
    int c = threadIdx.x;
    float mu  = stats[c] * (1.0f / N_NODES);
    float var = stats[DIM + c] * (1.0f / N_NODES) - mu * mu;
    float sc  = rsqrtf(var + BN_EPS) * gamma[c];
    scsh[c] = sc;
    scsh[DIM + c] = beta[c] - mu * sc;
}

// final-layer BN apply: grouped bf16 in -> standard-layout fp32 out
__global__ __launch_bounds__(256) void k_bn(const uint4* __restrict__ in,
                                            const float* __restrict__ scsh,
                                            float4* __restrict__ outf){
    int i = blockIdx.x * 256 + threadIdx.x;         // 8-bf16 chunk index
    if (i >= N_NODES * DIM / 8) return;
    int row = i >> 4;
    int c = (i * 8) & (DIM - 1);
    int gg = c >> 5, wi = c & 31;
    uint4 raw = in[gg*(N_NODES*4) + row*4 + (wi >> 3)];
    float4 sc0 = *(const float4*)&scsh[c];
    float4 sc1 = *(const float4*)&scsh[c + 4];
    float4 sh0 = *(const float4*)&scsh[DIM + c];
    float4 sh1 = *(const float4*)&scsh[DIM + c + 4];
    unsigned int u[4] = {raw.x, raw.y, raw.z, raw.w};
    float v[8];
    #pragma unroll
    for (int j = 0; j < 4; j++){
        v[2*j]   = bf2f((unsigned short)(u[j] & 0xffff));
        v[2*j+1] = bf2f((unsigned short)(u[j] >> 16));
    }
    float4 r0, r1;
    r0.x = fmaf(v[0], sc0.x, sh0.x);
    r0.y = fmaf(v[1], sc0.y, sh0.y);
    r0.z = fmaf(v[2], sc0.z, sh0.z);
    r0.w = fmaf(v[3], sc0.w, sh0.w);
    r1.x = fmaf(v[4], sc1.x, sh1.x);
    r1.y = fmaf(v[5], sc1.y, sh1.y);
    r1.z = fmaf(v[6], sc1.z, sh1.z);
    r1.w = fmaf(v[7], sc1.w, sh1.w);
    outf[2*i]   = r0;
    outf[2*i+1] = r1;
}

// ---------------- launch ----------------

extern "C" void kernel_launch(void* const* d_in, const int* in_sizes, int n_in,
                              void* d_out, int out_size, void* d_ws, size_t ws_size,
                              hipStream_t stream){
    const float* x   = (const float*)d_in[0];
    const int*   src = (const int*)d_in[1];
    const int*   dst = src + N_EDGES;
    const float* Ws  = (const float*)d_in[2];
    const float* bs  = (const float*)d_in[3];
    const float* gs  = (const float*)d_in[4];
    const float* be  = (const float*)d_in[5];

    char* w = (char*)d_ws;
    int*   degcnt = (int*)(w);                         // 50000 i  [0,200000)
    float* stats  = (float*)(w + 200000);              // 1024 f
    float* scsh   = (float*)(w + 204096);              // 1024 f
    float* dis    = (float*)(w + 208192);              // 50000 f
    int*   rowptr = (int*)(w + 408192);                // 50001 i (pad)
    int*   wptr   = (int*)(w + 608208);                // 50000 i
    int*   bsum   = (int*)(w + 808208);                // 196 i (pad)
    float* bias2  = (float*)(w + 809232);              // 128 f
    unsigned short* wthi = (unsigned short*)(w + 809744);   // 16384 bf16
    unsigned short* wtlo = (unsigned short*)(w + 842512);   // 16384 bf16
    int2*  epair  = (int2*)(w + 875280);               // 800000 int2 (6.4MB)
    unsigned short* bufA = (unsigned short*)(w + 7275280);   // grouped bf16 (12.8MB)
    unsigned short* hb   = (unsigned short*)(w + 20075280);  // grouped bf16 (12.8MB)
    // total: 32,875,280 bytes

    k_zero<<<(51024 + 255)/256, 256, 0, stream>>>(degcnt, 51024);
    k_count<<<3125, 256, 0, stream>>>(dst, degcnt);
    k_scan1<<<SCAN_BLOCKS, 256, 0, stream>>>(degcnt, rowptr, bsum, dis);
    k_scan2<<<1, 256, 0, stream>>>(bsum);
    k_scan3<<<SCAN_BLOCKS, 256, 0, stream>>>(bsum, rowptr, wptr);
    k_fill<<<3125, 256, 0, stream>>>(src, dst, dis, wptr, epair);

    for (int L = 0; L < NLAYERS; L++){
        const float* Wl = Ws + L*DIM*DIM;
        if (L == 0){
            k_wprep<false><<<65, 256, 0, stream>>>(Wl, nullptr, wthi, wtlo, bias2);
            k_gemm<0><<<(N_NODES + 63)/64, 256, 0, stream>>>(x, wthi, wtlo,
                                                             bias2, hb);
        } else {
            k_wprep<true><<<65, 256, 0, stream>>>(Wl, scsh + (L-1)*256,
                                                  wthi, wtlo, bias2);
            k_gemm<1><<<(N_NODES + 63)/64, 256, 0, stream>>>(bufA, wthi, wtlo,
                                                             bias2, hb);
        }
        k_agg<<<2048, 256, 0, stream>>>(hb, rowptr, epair, dis, bs + L*DIM,
                                        bufA, stats + L*256);
        k_bnstat<<<1, 128, 0, stream>>>(stats + L*256, gs + L*DIM, be + L*DIM,
                                        scsh + L*256);
    }
    k_bn<<<3125, 256, 0, stream>>>((const uint4*)bufA, scsh + 3*256,
                                   (float4*)d_out);
}

// Round 11
// 595.358 us; speedup vs baseline: 1.1403x; 1.1403x over previous
//
#include <hip/hip_runtime.h>

#define N_NODES 50000
#define N_EDGES 800000
#define DIM 128
#define NLAYERS 4
#define BN_EPS 1e-5f
#define SCAN_BLOCKS 196   // ceil(N_NODES/256)
#define WSTRIDE 136       // 128 + 8 bf16 pad (LDS bank decorrelation)

typedef __attribute__((ext_vector_type(8))) short short8;
typedef __attribute__((ext_vector_type(4))) float f32x4;

__device__ __forceinline__ float bf2f(unsigned short u){
    union { unsigned int i; float f; } x; x.i = ((unsigned int)u) << 16; return x.f;
}
__device__ __forceinline__ unsigned short f2bf(float f){
    union { float f; unsigned int i; } x; x.f = f;
    unsigned int lsb = (x.i >> 16) & 1u;
    unsigned int r = x.i + 0x7fffu + lsb;
    return (unsigned short)(r >> 16);
}

// ---------------- prep kernels ----------------

__global__ __launch_bounds__(256) void k_zero(int* __restrict__ p, int n){
    int i = blockIdx.x * 256 + threadIdx.x;
    if (i < n) p[i] = 0;
}

__global__ __launch_bounds__(256) void k_count(const int* __restrict__ dst,
                                               int* __restrict__ degcnt){
    int e = blockIdx.x * 256 + threadIdx.x;
    if (e < N_EDGES) atomicAdd(&degcnt[dst[e]], 1);
}

// phase 1 + dis: per-block exclusive scan of degcnt; also dis = rsqrt(deg+1)
__global__ __launch_bounds__(256) void k_scan1(const int* __restrict__ degcnt,
                                               int* __restrict__ rowptr,
                                               int* __restrict__ bsum,
                                               float* __restrict__ dis){
    __shared__ int tmp[256];
    int t = threadIdx.x;
    int i = blockIdx.x * 256 + t;
    int v = (i < N_NODES) ? degcnt[i] : 0;
    if (i < N_NODES) dis[i] = rsqrtf((float)v + 1.0f);
    tmp[t] = v;
    __syncthreads();
    #pragma unroll
    for (int off = 1; off < 256; off <<= 1){
        int u = (t >= off) ? tmp[t - off] : 0;
        __syncthreads();
        tmp[t] += u;
        __syncthreads();
    }
    if (i < N_NODES) rowptr[i] = tmp[t] - v;
    if (t == 255) bsum[blockIdx.x] = tmp[255];
}

__global__ __launch_bounds__(256) void k_scan2(int* __restrict__ bsum){
    __shared__ int tmp[256];
    int t = threadIdx.x;
    int v = (t < SCAN_BLOCKS) ? bsum[t] : 0;
    tmp[t] = v;
    __syncthreads();
    #pragma unroll
    for (int off = 1; off < 256; off <<= 1){
        int u = (t >= off) ? tmp[t - off] : 0;
        __syncthreads();
        tmp[t] += u;
        __syncthreads();
    }
    if (t < SCAN_BLOCKS) bsum[t] = tmp[t] - v;
}

__global__ __launch_bounds__(256) void k_scan3(const int* __restrict__ bsum,
                                               int* __restrict__ rowptr,
                                               int* __restrict__ wptr){
    int i = blockIdx.x * 256 + threadIdx.x;
    if (i < N_NODES){
        int r = rowptr[i] + bsum[blockIdx.x];
        rowptr[i] = r; wptr[i] = r;
    }
    if (i == 0) rowptr[N_NODES] = N_EDGES;
}

__global__ __launch_bounds__(256) void k_fill(const int* __restrict__ src,
                                              const int* __restrict__ dst,
                                              const float* __restrict__ dis,
                                              int* __restrict__ wptr,
                                              int2* __restrict__ epair){
    int e = blockIdx.x * 256 + threadIdx.x;
    if (e < N_EDGES){
        int s = src[e], d = dst[e];
        float w = dis[s] * dis[d];
        int p = atomicAdd(&wptr[d], 1);
        int2 pr; pr.x = s; pr.y = __float_as_int(w);
        epair[p] = pr;
    }
}

// W' = diag(sc)*W; write W'^T (c-major) bf16 hi/lo. Block 64 computes
// bias2[c] = sum_k sh[k]*W[k][c].
template<bool HAS>
__global__ __launch_bounds__(256) void k_wprep(const float* __restrict__ W,
                                               const float* __restrict__ scsh,
                                               unsigned short* __restrict__ wthi,
                                               unsigned short* __restrict__ wtlo,
                                               float* __restrict__ bias2){
    int tid = threadIdx.x;
    if (blockIdx.x < 64){
        int idx = blockIdx.x * 256 + tid;        // 0..16383
        int c = idx >> 7, k = idx & 127;
        float v = W[k*DIM + c];
        if (HAS) v *= scsh[k];
        unsigned short hi = f2bf(v);
        float lo = v - bf2f(hi);
        wthi[c*DIM + k] = hi;
        wtlo[c*DIM + k] = f2bf(lo);
    } else {
        __shared__ float part[256];
        int c = tid >> 1, half = tid & 1;
        float acc = 0.f;
        if (HAS){
            int k0 = half * 64;
            #pragma unroll 4
            for (int k = k0; k < k0 + 64; k++)
                acc = fmaf(scsh[DIM + k], W[k*DIM + c], acc);
        }
        part[tid] = acc;
        __syncthreads();
        if (half == 0) bias2[c] = part[2*c] + part[2*c + 1];
    }
}

// ---------------- per-layer kernels ----------------
// Grouped feature layout: t[g][node][32 cols], g = col>>5 (3.2MB/slice).

// MFMA GEMM: h = z @ W' + bias2.  MODE 0: z = x fp32 std layout. MODE 1: z
// grouped bf16. W'^T hi/lo bf16 staged in LDS, h grouped bf16.
// 64 rows/block, 4 waves; wave = 16 rows x 128 cols = 8 mfma 16x16x32, K=128.
template<int MODE>
__global__ __launch_bounds__(256) void k_gemm(const void* __restrict__ zraw,
                                              const unsigned short* __restrict__ wthi,
                                              const unsigned short* __restrict__ wtlo,
                                              const float* __restrict__ bias2,
                                              unsigned short* __restrict__ hb){
    __shared__ short whi[DIM * WSTRIDE];       // 34816 B
    __shared__ short wlo[DIM * WSTRIDE];       // 34816 B
    int tid = threadIdx.x;

    {
        const uint4* gh = (const uint4*)wthi;
        const uint4* gl = (const uint4*)wtlo;
        #pragma unroll
        for (int it = 0; it < 8; it++){
            int ch = tid + 256*it;             // 0..2047
            int c = ch >> 4, k8 = ch & 15;
            int off = c*WSTRIDE + k8*8;
            *(uint4*)&whi[off] = gh[ch];
            *(uint4*)&wlo[off] = gl[ch];
        }
    }
    __syncthreads();

    int lane = tid & 63;
    int wv   = tid >> 6;
    int m = lane & 15;
    int q = lane >> 4;
    int row0 = blockIdx.x * 64 + wv * 16;
    int arow = row0 + m;
    bool avalid = arow < N_NODES;

    f32x4 acc[8];
    #pragma unroll
    for (int t = 0; t < 8; t++) acc[t] = (f32x4){0.f, 0.f, 0.f, 0.f};

    #pragma unroll
    for (int g = 0; g < 4; g++){               // k-step = feature group
        short8 a = {0,0,0,0,0,0,0,0};
        if (avalid){
            if (MODE == 0){
                const float* xp = (const float*)zraw + (size_t)arow*DIM + g*32 + q*8;
                float4 v0 = *(const float4*)xp;
                float4 v1 = *(const float4*)(xp + 4);
                a[0] = (short)f2bf(v0.x); a[1] = (short)f2bf(v0.y);
                a[2] = (short)f2bf(v0.z); a[3] = (short)f2bf(v0.w);
                a[4] = (short)f2bf(v1.x); a[5] = (short)f2bf(v1.y);
                a[6] = (short)f2bf(v1.z); a[7] = (short)f2bf(v1.w);
            } else {
                a = *(const short8*)((const unsigned short*)zraw
                      + (size_t)g*N_NODES*32 + (size_t)arow*32 + q*8);
            }
        }
        #pragma unroll
        for (int t = 0; t < 8; t++){
            int col = t*16 + m;
            int off = col*WSTRIDE + g*32 + q*8;
            short8 bh = *(const short8*)&whi[off];
            short8 bl = *(const short8*)&wlo[off];
            acc[t] = __builtin_amdgcn_mfma_f32_16x16x32_bf16(a, bh, acc[t], 0, 0, 0);
            acc[t] = __builtin_amdgcn_mfma_f32_16x16x32_bf16(a, bl, acc[t], 0, 0, 0);
        }
    }

    #pragma unroll
    for (int t = 0; t < 8; t++){
        int colg = t*16 + m;
        float bz = bias2[colg];
        size_t base = (size_t)(t >> 1)*N_NODES*32 + (t & 1)*16 + m;
        #pragma unroll
        for (int r = 0; r < 4; r++){
            int row = row0 + q*4 + r;
            if (row < N_NODES)
                hb[base + (size_t)row*32] = f2bf(acc[t][r] + bz);
        }
    }
}

// CSR aggregation + bias + ReLU + per-column stats, feature-group partitioned.
// group = blockIdx&3. 16 lanes/edge (ushort2), 4 edges/wave-gather, 16-edge
// main loop (4 gathers in flight). Next-node header (rowptr/hv/dis) is
// prefetched before the edge loop to hide per-node startup latency.
__global__ __launch_bounds__(256) void k_agg(const unsigned short* __restrict__ h,
                                             const int* __restrict__ rowptr,
                                             const int2* __restrict__ epair,
                                             const float* __restrict__ dis,
                                             const float* __restrict__ bias,
                                             unsigned short* __restrict__ out,
                                             float* __restrict__ stats){
    int lane = threadIdx.x & 63;
    int w    = threadIdx.x >> 6;
    int g    = blockIdx.x & 3;
    int sub  = lane >> 4;
    int cp   = lane & 15;
    const ushort2* hg = (const ushort2*)(h + (size_t)g * N_NODES * 32);
    ushort2* og = (ushort2*)(out + (size_t)g * N_NODES * 32);
    float b0 = bias[g*32 + 2*cp], b1 = bias[g*32 + 2*cp + 1];
    float s0 = 0.f, s1 = 0.f, q0 = 0.f, q1 = 0.f;
    int bg = blockIdx.x >> 2;
    int nstride = (gridDim.x >> 2) * 4;

    int node = bg*4 + w;
    int ne0 = 0, ne1 = 0;
    ushort2 nhv; nhv.x = 0; nhv.y = 0;
    float ndi = 0.f;
    if (node < N_NODES){
        ne0 = rowptr[node];
        ne1 = rowptr[node + 1];
        nhv = hg[node*16 + cp];
        ndi = dis[node];
    }

    while (node < N_NODES){
        int e0 = ne0, e1 = ne1;
        ushort2 hv = nhv;
        float di = ndi;

        int nnext = node + nstride;
        if (nnext < N_NODES){                  // prefetch next node header
            ne0 = rowptr[nnext];
            ne1 = rowptr[nnext + 1];
            nhv = hg[nnext*16 + cp];
            ndi = dis[nnext];
        }

        float pa0 = 0.f, pa1 = 0.f, pb0 = 0.f, pb1 = 0.f;
        float pc0 = 0.f, pc1 = 0.f, pd0 = 0.f, pd1 = 0.f;
        if (sub == 0){
            float dii = di * di;
            pa0 = bf2f(hv.x) * dii; pa1 = bf2f(hv.y) * dii;
        }
        int e = e0;
        for (; e + 16 <= e1; e += 16){
            int2 P0 = epair[e + sub];
            int2 P1 = epair[e + 4 + sub];
            int2 P2 = epair[e + 8 + sub];
            int2 P3 = epair[e + 12 + sub];
            ushort2 X0 = hg[P0.x*16 + cp];
            ushort2 X1 = hg[P1.x*16 + cp];
            ushort2 X2 = hg[P2.x*16 + cp];
            ushort2 X3 = hg[P3.x*16 + cp];
            float w0 = __int_as_float(P0.y), w1 = __int_as_float(P1.y);
            float w2 = __int_as_float(P2.y), w3 = __int_as_float(P3.y);
            pa0 = fmaf(bf2f(X0.x), w0, pa0); pa1 = fmaf(bf2f(X0.y), w0, pa1);
            pb0 = fmaf(bf2f(X1.x), w1, pb0); pb1 = fmaf(bf2f(X1.y), w1, pb1);
            pc0 = fmaf(bf2f(X2.x), w2, pc0); pc1 = fmaf(bf2f(X2.y), w2, pc1);
            pd0 = fmaf(bf2f(X3.x), w3, pd0); pd1 = fmaf(bf2f(X3.y), w3, pd1);
        }
        for (; e + 8 <= e1; e += 8){
            int2 P0 = epair[e + sub];
            int2 P1 = epair[e + 4 + sub];
            ushort2 X0 = hg[P0.x*16 + cp];
            ushort2 X1 = hg[P1.x*16 + cp];
            float w0 = __int_as_float(P0.y), w1 = __int_as_float(P1.y);
            pa0 = fmaf(bf2f(X0.x), w0, pa0); pa1 = fmaf(bf2f(X0.y), w0, pa1);
            pb0 = fmaf(bf2f(X1.x), w1, pb0); pb1 = fmaf(bf2f(X1.y), w1, pb1);
        }
        for (; e < e1; e += 4){
            int ide = e + sub;
            int2 pr = (ide < e1) ? epair[ide] : make_int2(0, 0);
            ushort2 xv = hg[pr.x*16 + cp];
            float we = __int_as_float(pr.y);   // 0.0f for masked lanes
            pa0 = fmaf(bf2f(xv.x), we, pa0);
            pa1 = fmaf(bf2f(xv.y), we, pa1);
        }
        float r0 = (pa0 + pb0) + (pc0 + pd0);
        float r1 = (pa1 + pb1) + (pc1 + pd1);
        r0 += __shfl_xor(r0, 16); r1 += __shfl_xor(r1, 16);
        r0 += __shfl_xor(r0, 32); r1 += __shfl_xor(r1, 32);
        if (sub == 0){
            float a0 = fmaxf(r0 + b0, 0.f);
            float a1 = fmaxf(r1 + b1, 0.f);
            ushort2 ov; ov.x = f2bf(a0); ov.y = f2bf(a1);
            og[node*16 + cp] = ov;
            s0 += a0; s1 += a1; q0 += a0*a0; q1 += a1*a1;
        }
        node = nnext;
    }

    __shared__ float red[4][16][4];
    if (sub == 0){
        red[w][cp][0] = s0; red[w][cp][1] = s1;
        red[w][cp][2] = q0; red[w][cp][3] = q1;
    }
    __syncthreads();
    if (w == 0 && sub == 0){
        #pragma unroll
        for (int ww = 1; ww < 4; ww++){
            s0 += red[ww][cp][0]; s1 += red[ww][cp][1];
            q0 += red[ww][cp][2]; q1 += red[ww][cp][3];
        }
        int c = g*32 + 2*cp;
        atomicAdd(&stats[c],         s0);
        atomicAdd(&stats[c + 1],     s1);
        atomicAdd(&stats[DIM + c],     q0);
        atomicAdd(&stats[DIM + c + 1], q1);
    }
}

// stats -> per-column scale/shift:  sc = rstd*gamma, sh = beta - mu*sc
__global__ void k_bnstat(const float* __restrict__ stats,
                         const float* __restrict__ gamma,
                         const float* __restrict__ beta,
                         float* __restrict__ scsh){
    int c = threadIdx.x;
    float mu  = stats[c] * (1.0f / N_NODES);
    float var = stats[DIM + c] * (1.0f / N_NODES) - mu * mu;
    float sc  = rsqrtf(var + BN_EPS) * gamma[c];
    scsh[c] = sc;
    scsh[DIM + c] = beta[c] - mu * sc;
}

// final-layer BN apply: grouped bf16 in -> standard-layout fp32 out
__global__ __launch_bounds__(256) void k_bn(const uint4* __restrict__ in,
                                            const float* __restrict__ scsh,
                                            float4* __restrict__ outf){
    int i = blockIdx.x * 256 + threadIdx.x;         // 8-bf16 chunk index
    if (i >= N_NODES * DIM / 8) return;
    int row = i >> 4;
    int c = (i * 8) & (DIM - 1);
    int gg = c >> 5, wi = c & 31;
    uint4 raw = in[gg*(N_NODES*4) + row*4 + (wi >> 3)];
    float4 sc0 = *(const float4*)&scsh[c];
    float4 sc1 = *(const float4*)&scsh[c + 4];
    float4 sh0 = *(const float4*)&scsh[DIM + c];
    float4 sh1 = *(const float4*)&scsh[DIM + c + 4];
    unsigned int u[4] = {raw.x, raw.y, raw.z, raw.w};
    float v[8];
    #pragma unroll
    for (int j = 0; j < 4; j++){
        v[2*j]   = bf2f((unsigned short)(u[j] & 0xffff));
        v[2*j+1] = bf2f((unsigned short)(u[j] >> 16));
    }
    float4 r0, r1;
    r0.x = fmaf(v[0], sc0.x, sh0.x);
    r0.y = fmaf(v[1], sc0.y, sh0.y);
    r0.z = fmaf(v[2], sc0.z, sh0.z);
    r0.w = fmaf(v[3], sc0.w, sh0.w);
    r1.x = fmaf(v[4], sc1.x, sh1.x);
    r1.y = fmaf(v[5], sc1.y, sh1.y);
    r1.z = fmaf(v[6], sc1.z, sh1.z);
    r1.w = fmaf(v[7], sc1.w, sh1.w);
    outf[2*i]   = r0;
    outf[2*i+1] = r1;
}

// ---------------- launch ----------------

extern "C" void kernel_launch(void* const* d_in, const int* in_sizes, int n_in,
                              void* d_out, int out_size, void* d_ws, size_t ws_size,
                              hipStream_t stream){
    const float* x   = (const float*)d_in[0];
    const int*   src = (const int*)d_in[1];
    const int*   dst = src + N_EDGES;
    const float* Ws  = (const float*)d_in[2];
    const float* bs  = (const float*)d_in[3];
    const float* gs  = (const float*)d_in[4];
    const float* be  = (const float*)d_in[5];

    char* w = (char*)d_ws;
    int*   degcnt = (int*)(w);                         // 50000 i  [0,200000)
    float* stats  = (float*)(w + 200000);              // 1024 f
    float* scsh   = (float*)(w + 204096);              // 1024 f
    float* dis    = (float*)(w + 208192);              // 50000 f
    int*   rowptr = (int*)(w + 408192);                // 50001 i (pad)
    int*   wptr   = (int*)(w + 608208);                // 50000 i
    int*   bsum   = (int*)(w + 808208);                // 196 i (pad)
    float* bias2  = (float*)(w + 809232);              // 128 f
    unsigned short* wthi = (unsigned short*)(w + 809744);   // 16384 bf16
    unsigned short* wtlo = (unsigned short*)(w + 842512);   // 16384 bf16
    int2*  epair  = (int2*)(w + 875280);               // 800000 int2 (6.4MB)
    unsigned short* bufA = (unsigned short*)(w + 7275280);   // grouped bf16 (12.8MB)
    unsigned short* hb   = (unsigned short*)(w + 20075280);  // grouped bf16 (12.8MB)
    // total: 32,875,280 bytes

    k_zero<<<(51024 + 255)/256, 256, 0, stream>>>(degcnt, 51024);
    k_count<<<3125, 256, 0, stream>>>(dst, degcnt);
    k_scan1<<<SCAN_BLOCKS, 256, 0, stream>>>(degcnt, rowptr, bsum, dis);
    k_scan2<<<1, 256, 0, stream>>>(bsum);
    k_scan3<<<SCAN_BLOCKS, 256, 0, stream>>>(bsum, rowptr, wptr);
    k_fill<<<3125, 256, 0, stream>>>(src, dst, dis, wptr, epair);

    for (int L = 0; L < NLAYERS; L++){
        const float* Wl = Ws + L*DIM*DIM;
        if (L == 0){
            k_wprep<false><<<65, 256, 0, stream>>>(Wl, nullptr, wthi, wtlo, bias2);
            k_gemm<0><<<(N_NODES + 63)/64, 256, 0, stream>>>(x, wthi, wtlo,
                                                             bias2, hb);
        } else {
            k_wprep<true><<<65, 256, 0, stream>>>(Wl, scsh + (L-1)*256,
                                                  wthi, wtlo, bias2);
            k_gemm<1><<<(N_NODES + 63)/64, 256, 0, stream>>>(bufA, wthi, wtlo,
                                                             bias2, hb);
        }
        k_agg<<<2048, 256, 0, stream>>>(hb, rowptr, epair, dis, bs + L*DIM,
                                        bufA, stats + L*256);
        k_bnstat<<<1, 128, 0, stream>>>(stats + L*256, gs + L*DIM, be + L*DIM,
                                        scsh + L*256);
    }
    k_bn<<<3125, 256, 0, stream>>>((const uint4*)bufA, scsh + 3*256,
                                   (float4*)d_out);
}

// Round 12
// 593.684 us; speedup vs baseline: 1.1436x; 1.0028x over previous
//
#include <hip/hip_runtime.h>

#define N_NODES 50000
#define N_EDGES 800000
#define DIM 128
#define NLAYERS 4
#define BN_EPS 1e-5f
#define SCAN_BLOCKS 196   // ceil(N_NODES/256)
#define WSTRIDE 136       // 128 + 8 bf16 pad (LDS bank decorrelation)

typedef __attribute__((ext_vector_type(8))) short short8;
typedef __attribute__((ext_vector_type(4))) float f32x4;

__device__ __forceinline__ float bf2f(unsigned short u){
    union { unsigned int i; float f; } x; x.i = ((unsigned int)u) << 16; return x.f;
}
__device__ __forceinline__ unsigned short f2bf(float f){
    union { float f; unsigned int i; } x; x.f = f;
    unsigned int lsb = (x.i >> 16) & 1u;
    unsigned int r = x.i + 0x7fffu + lsb;
    return (unsigned short)(r >> 16);
}

struct P4 { int2 a, b, c, d; };

__device__ __forceinline__ P4 loadP(const int2* __restrict__ ep, int base,
                                    int sub, int lim){
    P4 p;
    int i0 = base + sub, i1 = base + 4 + sub, i2 = base + 8 + sub, i3 = base + 12 + sub;
    p.a = (i0 < lim) ? ep[i0] : make_int2(0, 0);
    p.b = (i1 < lim) ? ep[i1] : make_int2(0, 0);
    p.c = (i2 < lim) ? ep[i2] : make_int2(0, 0);
    p.d = (i3 < lim) ? ep[i3] : make_int2(0, 0);
    return p;
}

// ---------------- prep kernels ----------------

__global__ __launch_bounds__(256) void k_zero(int* __restrict__ p, int n){
    int i = blockIdx.x * 256 + threadIdx.x;
    if (i < n) p[i] = 0;
}

__global__ __launch_bounds__(256) void k_count(const int* __restrict__ dst,
                                               int* __restrict__ degcnt){
    int e = blockIdx.x * 256 + threadIdx.x;
    if (e < N_EDGES) atomicAdd(&degcnt[dst[e]], 1);
}

// phase 1 + dis: per-block exclusive scan of degcnt; also dis = rsqrt(deg+1)
__global__ __launch_bounds__(256) void k_scan1(const int* __restrict__ degcnt,
                                               int* __restrict__ rowptr,
                                               int* __restrict__ bsum,
                                               float* __restrict__ dis){
    __shared__ int tmp[256];
    int t = threadIdx.x;
    int i = blockIdx.x * 256 + t;
    int v = (i < N_NODES) ? degcnt[i] : 0;
    if (i < N_NODES) dis[i] = rsqrtf((float)v + 1.0f);
    tmp[t] = v;
    __syncthreads();
    #pragma unroll
    for (int off = 1; off < 256; off <<= 1){
        int u = (t >= off) ? tmp[t - off] : 0;
        __syncthreads();
        tmp[t] += u;
        __syncthreads();
    }
    if (i < N_NODES) rowptr[i] = tmp[t] - v;
    if (t == 255) bsum[blockIdx.x] = tmp[255];
}

__global__ __launch_bounds__(256) void k_scan2(int* __restrict__ bsum){
    __shared__ int tmp[256];
    int t = threadIdx.x;
    int v = (t < SCAN_BLOCKS) ? bsum[t] : 0;
    tmp[t] = v;
    __syncthreads();
    #pragma unroll
    for (int off = 1; off < 256; off <<= 1){
        int u = (t >= off) ? tmp[t - off] : 0;
        __syncthreads();
        tmp[t] += u;
        __syncthreads();
    }
    if (t < SCAN_BLOCKS) bsum[t] = tmp[t] - v;
}

__global__ __launch_bounds__(256) void k_scan3(const int* __restrict__ bsum,
                                               int* __restrict__ rowptr,
                                               int* __restrict__ wptr){
    int i = blockIdx.x * 256 + threadIdx.x;
    if (i < N_NODES){
        int r = rowptr[i] + bsum[blockIdx.x];
        rowptr[i] = r; wptr[i] = r;
    }
    if (i == 0) rowptr[N_NODES] = N_EDGES;
}

__global__ __launch_bounds__(256) void k_fill(const int* __restrict__ src,
                                              const int* __restrict__ dst,
                                              const float* __restrict__ dis,
                                              int* __restrict__ wptr,
                                              int2* __restrict__ epair){
    int e = blockIdx.x * 256 + threadIdx.x;
    if (e < N_EDGES){
        int s = src[e], d = dst[e];
        float w = dis[s] * dis[d];
        int p = atomicAdd(&wptr[d], 1);
        int2 pr; pr.x = s; pr.y = __float_as_int(w);
        epair[p] = pr;
    }
}

// W' = diag(sc)*W; write W'^T (c-major) bf16 hi/lo. Block 64 computes
// bias2[c] = sum_k sh[k]*W[k][c].
template<bool HAS>
__global__ __launch_bounds__(256) void k_wprep(const float* __restrict__ W,
                                               const float* __restrict__ scsh,
                                               unsigned short* __restrict__ wthi,
                                               unsigned short* __restrict__ wtlo,
                                               float* __restrict__ bias2){
    int tid = threadIdx.x;
    if (blockIdx.x < 64){
        int idx = blockIdx.x * 256 + tid;        // 0..16383
        int c = idx >> 7, k = idx & 127;
        float v = W[k*DIM + c];
        if (HAS) v *= scsh[k];
        unsigned short hi = f2bf(v);
        float lo = v - bf2f(hi);
        wthi[c*DIM + k] = hi;
        wtlo[c*DIM + k] = f2bf(lo);
    } else {
        __shared__ float part[256];
        int c = tid >> 1, half = tid & 1;
        float acc = 0.f;
        if (HAS){
            int k0 = half * 64;
            #pragma unroll 4
            for (int k = k0; k < k0 + 64; k++)
                acc = fmaf(scsh[DIM + k], W[k*DIM + c], acc);
        }
        part[tid] = acc;
        __syncthreads();
        if (half == 0) bias2[c] = part[2*c] + part[2*c + 1];
    }
}

// ---------------- per-layer kernels ----------------
// Grouped feature layout: t[g][node][32 cols], g = col>>5 (3.2MB/slice).

// MFMA GEMM: h = z @ W' + bias2.  MODE 0: z = x fp32 std layout. MODE 1: z
// grouped bf16. W'^T hi/lo bf16 staged in LDS, h grouped bf16.
// 64 rows/block, 4 waves; wave = 16 rows x 128 cols = 8 mfma 16x16x32, K=128.
template<int MODE>
__global__ __launch_bounds__(256) void k_gemm(const void* __restrict__ zraw,
                                              const unsigned short* __restrict__ wthi,
                                              const unsigned short* __restrict__ wtlo,
                                              const float* __restrict__ bias2,
                                              unsigned short* __restrict__ hb){
    __shared__ short whi[DIM * WSTRIDE];       // 34816 B
    __shared__ short wlo[DIM * WSTRIDE];       // 34816 B
    int tid = threadIdx.x;

    {
        const uint4* gh = (const uint4*)wthi;
        const uint4* gl = (const uint4*)wtlo;
        #pragma unroll
        for (int it = 0; it < 8; it++){
            int ch = tid + 256*it;             // 0..2047
            int c = ch >> 4, k8 = ch & 15;
            int off = c*WSTRIDE + k8*8;
            *(uint4*)&whi[off] = gh[ch];
            *(uint4*)&wlo[off] = gl[ch];
        }
    }
    __syncthreads();

    int lane = tid & 63;
    int wv   = tid >> 6;
    int m = lane & 15;
    int q = lane >> 4;
    int row0 = blockIdx.x * 64 + wv * 16;
    int arow = row0 + m;
    bool avalid = arow < N_NODES;

    f32x4 acc[8];
    #pragma unroll
    for (int t = 0; t < 8; t++) acc[t] = (f32x4){0.f, 0.f, 0.f, 0.f};

    #pragma unroll
    for (int g = 0; g < 4; g++){               // k-step = feature group
        short8 a = {0,0,0,0,0,0,0,0};
        if (avalid){
            if (MODE == 0){
                const float* xp = (const float*)zraw + (size_t)arow*DIM + g*32 + q*8;
                float4 v0 = *(const float4*)xp;
                float4 v1 = *(const float4*)(xp + 4);
                a[0] = (short)f2bf(v0.x); a[1] = (short)f2bf(v0.y);
                a[2] = (short)f2bf(v0.z); a[3] = (short)f2bf(v0.w);
                a[4] = (short)f2bf(v1.x); a[5] = (short)f2bf(v1.y);
                a[6] = (short)f2bf(v1.z); a[7] = (short)f2bf(v1.w);
            } else {
                a = *(const short8*)((const unsigned short*)zraw
                      + (size_t)g*N_NODES*32 + (size_t)arow*32 + q*8);
            }
        }
        #pragma unroll
        for (int t = 0; t < 8; t++){
            int col = t*16 + m;
            int off = col*WSTRIDE + g*32 + q*8;
            short8 bh = *(const short8*)&whi[off];
            short8 bl = *(const short8*)&wlo[off];
            acc[t] = __builtin_amdgcn_mfma_f32_16x16x32_bf16(a, bh, acc[t], 0, 0, 0);
            acc[t] = __builtin_amdgcn_mfma_f32_16x16x32_bf16(a, bl, acc[t], 0, 0, 0);
        }
    }

    #pragma unroll
    for (int t = 0; t < 8; t++){
        int colg = t*16 + m;
        float bz = bias2[colg];
        size_t base = (size_t)(t >> 1)*N_NODES*32 + (t & 1)*16 + m;
        #pragma unroll
        for (int r = 0; r < 4; r++){
            int row = row0 + q*4 + r;
            if (row < N_NODES)
                hb[base + (size_t)row*32] = f2bf(acc[t][r] + bz);
        }
    }
}

// CSR aggregation + bias + ReLU + per-column stats, feature-group partitioned.
// group = blockIdx&3. 16 lanes/edge (ushort2), unified masked 16-edge chunks.
// Pipelining: next node's header AND first epair chunk prefetched during the
// current node's compute; within a node, chunk i+1 epairs issued before
// chunk i's h-gathers.
__global__ __launch_bounds__(256) void k_agg(const unsigned short* __restrict__ h,
                                             const int* __restrict__ rowptr,
                                             const int2* __restrict__ epair,
                                             const float* __restrict__ dis,
                                             const float* __restrict__ bias,
                                             unsigned short* __restrict__ out,
                                             float* __restrict__ stats){
    int lane = threadIdx.x & 63;
    int w    = threadIdx.x >> 6;
    int g    = blockIdx.x & 3;
    int sub  = lane >> 4;
    int cp   = lane & 15;
    const ushort2* hg = (const ushort2*)(h + (size_t)g * N_NODES * 32);
    ushort2* og = (ushort2*)(out + (size_t)g * N_NODES * 32);
    float b0 = bias[g*32 + 2*cp], b1 = bias[g*32 + 2*cp + 1];
    float s0 = 0.f, s1 = 0.f, q0 = 0.f, q1 = 0.f;
    int bg = blockIdx.x >> 2;
    int nstride = (gridDim.x >> 2) * 4;

    int node = bg*4 + w;
    int ne0 = 0, ne1 = 0;
    ushort2 nhv; nhv.x = 0; nhv.y = 0;
    float ndi = 0.f;
    P4 nP = {{0,0},{0,0},{0,0},{0,0}};
    if (node < N_NODES){
        ne0 = rowptr[node];
        ne1 = rowptr[node + 1];
        nhv = hg[node*16 + cp];
        ndi = dis[node];
        nP  = loadP(epair, ne0, sub, ne1);
    }

    while (node < N_NODES){
        int e0 = ne0, e1 = ne1;
        ushort2 hv = nhv;
        float di = ndi;
        P4 P = nP;

        int nnext = node + nstride;
        if (nnext < N_NODES){                  // prefetch next node header
            ne0 = rowptr[nnext];
            ne1 = rowptr[nnext + 1];
            nhv = hg[nnext*16 + cp];
            ndi = dis[nnext];
        } else { ne0 = 0; ne1 = 0; }

        float pa0 = 0.f, pa1 = 0.f, pb0 = 0.f, pb1 = 0.f;
        float pc0 = 0.f, pc1 = 0.f, pd0 = 0.f, pd1 = 0.f;
        if (sub == 0){
            float dii = di * di;
            pa0 = bf2f(hv.x) * dii; pa1 = bf2f(hv.y) * dii;
        }

        int e = e0;
        while (e < e1){
            int en = e + 16;
            P4 Pn = {{0,0},{0,0},{0,0},{0,0}};
            if (en < e1) Pn = loadP(epair, en, sub, e1);   // pipeline epairs
            ushort2 X0 = hg[P.a.x*16 + cp];
            ushort2 X1 = hg[P.b.x*16 + cp];
            ushort2 X2 = hg[P.c.x*16 + cp];
            ushort2 X3 = hg[P.d.x*16 + cp];
            float w0 = __int_as_float(P.a.y), w1 = __int_as_float(P.b.y);
            float w2 = __int_as_float(P.c.y), w3 = __int_as_float(P.d.y);
            pa0 = fmaf(bf2f(X0.x), w0, pa0); pa1 = fmaf(bf2f(X0.y), w0, pa1);
            pb0 = fmaf(bf2f(X1.x), w1, pb0); pb1 = fmaf(bf2f(X1.y), w1, pb1);
            pc0 = fmaf(bf2f(X2.x), w2, pc0); pc1 = fmaf(bf2f(X2.y), w2, pc1);
            pd0 = fmaf(bf2f(X3.x), w3, pd0); pd1 = fmaf(bf2f(X3.y), w3, pd1);
            P = Pn;
            e = en;
        }

        float r0 = (pa0 + pb0) + (pc0 + pd0);
        float r1 = (pa1 + pb1) + (pc1 + pd1);
        r0 += __shfl_xor(r0, 16); r1 += __shfl_xor(r1, 16);
        r0 += __shfl_xor(r0, 32); r1 += __shfl_xor(r1, 32);
        if (sub == 0){
            float a0 = fmaxf(r0 + b0, 0.f);
            float a1 = fmaxf(r1 + b1, 0.f);
            ushort2 ov; ov.x = f2bf(a0); ov.y = f2bf(a1);
            og[node*16 + cp] = ov;
            s0 += a0; s1 += a1; q0 += a0*a0; q1 += a1*a1;
        }

        if (nnext < N_NODES)                   // prefetch next node's chunk 0
            nP = loadP(epair, ne0, sub, ne1);
        node = nnext;
    }

    __shared__ float red[4][16][4];
    if (sub == 0){
        red[w][cp][0] = s0; red[w][cp][1] = s1;
        red[w][cp][2] = q0; red[w][cp][3] = q1;
    }
    __syncthreads();
    if (w == 0 && sub == 0){
        #pragma unroll
        for (int ww = 1; ww < 4; ww++){
            s0 += red[ww][cp][0]; s1 += red[ww][cp][1];
            q0 += red[ww][cp][2]; q1 += red[ww][cp][3];
        }
        int c = g*32 + 2*cp;
        atomicAdd(&stats[c],         s0);
        atomicAdd(&stats[c + 1],     s1);
        atomicAdd(&stats[DIM + c],     q0);
        atomicAdd(&stats[DIM + c + 1], q1);
    }
}

// stats -> per-column scale/shift:  sc = rstd*gamma, sh = beta - mu*sc
__global__ void k_bnstat(const float* __restrict__ stats,
                         const float* __restrict__ gamma,
                         const float* __restrict__ beta,
                         float* __restrict__ scsh){
    int c = threadIdx.x;
    float mu  = stats[c] * (1.0f / N_NODES);
    float var = stats[DIM + c] * (1.0f / N_NODES) - mu * mu;
    float sc  = rsqrtf(var + BN_EPS) * gamma[c];
    scsh[c] = sc;
    scsh[DIM + c] = beta[c] - mu * sc;
}

// final-layer BN apply: grouped bf16 in -> standard-layout fp32 out
__global__ __launch_bounds__(256) void k_bn(const uint4* __restrict__ in,
                                            const float* __restrict__ scsh,
                                            float4* __restrict__ outf){
    int i = blockIdx.x * 256 + threadIdx.x;         // 8-bf16 chunk index
    if (i >= N_NODES * DIM / 8) return;
    int row = i >> 4;
    int c = (i * 8) & (DIM - 1);
    int gg = c >> 5, wi = c & 31;
    uint4 raw = in[gg*(N_NODES*4) + row*4 + (wi >> 3)];
    float4 sc0 = *(const float4*)&scsh[c];
    float4 sc1 = *(const float4*)&scsh[c + 4];
    float4 sh0 = *(const float4*)&scsh[DIM + c];
    float4 sh1 = *(const float4*)&scsh[DIM + c + 4];
    unsigned int u[4] = {raw.x, raw.y, raw.z, raw.w};
    float v[8];
    #pragma unroll
    for (int j = 0; j < 4; j++){
        v[2*j]   = bf2f((unsigned short)(u[j] & 0xffff));
        v[2*j+1] = bf2f((unsigned short)(u[j] >> 16));
    }
    float4 r0, r1;
    r0.x = fmaf(v[0], sc0.x, sh0.x);
    r0.y = fmaf(v[1], sc0.y, sh0.y);
    r0.z = fmaf(v[2], sc0.z, sh0.z);
    r0.w = fmaf(v[3], sc0.w, sh0.w);
    r1.x = fmaf(v[4], sc1.x, sh1.x);
    r1.y = fmaf(v[5], sc1.y, sh1.y);
    r1.z = fmaf(v[6], sc1.z, sh1.z);
    r1.w = fmaf(v[7], sc1.w, sh1.w);
    outf[2*i]   = r0;
    outf[2*i+1] = r1;
}

// ---------------- launch ----------------

extern "C" void kernel_launch(void* const* d_in, const int* in_sizes, int n_in,
                              void* d_out, int out_size, void* d_ws, size_t ws_size,
                              hipStream_t stream){
    const float* x   = (const float*)d_in[0];
    const int*   src = (const int*)d_in[1];
    const int*   dst = src + N_EDGES;
    const float* Ws  = (const float*)d_in[2];
    const float* bs  = (const float*)d_in[3];
    const float* gs  = (const float*)d_in[4];
    const float* be  = (const float*)d_in[5];

    char* w = (char*)d_ws;
    int*   degcnt = (int*)(w);                         // 50000 i  [0,200000)
    float* stats  = (float*)(w + 200000);              // 1024 f
    float* scsh   = (float*)(w + 204096);              // 1024 f
    float* dis    = (float*)(w + 208192);              // 50000 f
    int*   rowptr = (int*)(w + 408192);                // 50001 i (pad)
    int*   wptr   = (int*)(w + 608208);                // 50000 i
    int*   bsum   = (int*)(w + 808208);                // 196 i (pad)
    float* bias2  = (float*)(w + 809232);              // 128 f
    unsigned short* wthi = (unsigned short*)(w + 809744);   // 16384 bf16
    unsigned short* wtlo = (unsigned short*)(w + 842512);   // 16384 bf16
    int2*  epair  = (int2*)(w + 875280);               // 800000 int2 (6.4MB)
    unsigned short* bufA = (unsigned short*)(w + 7275280);   // grouped bf16 (12.8MB)
    unsigned short* hb   = (unsigned short*)(w + 20075280);  // grouped bf16 (12.8MB)
    // total: 32,875,280 bytes

    k_zero<<<(51024 + 255)/256, 256, 0, stream>>>(degcnt, 51024);
    k_count<<<3125, 256, 0, stream>>>(dst, degcnt);
    k_scan1<<<SCAN_BLOCKS, 256, 0, stream>>>(degcnt, rowptr, bsum, dis);
    k_scan2<<<1, 256, 0, stream>>>(bsum);
    k_scan3<<<SCAN_BLOCKS, 256, 0, stream>>>(bsum, rowptr, wptr);
    k_fill<<<3125, 256, 0, stream>>>(src, dst, dis, wptr, epair);

    for (int L = 0; L < NLAYERS; L++){
        const float* Wl = Ws + L*DIM*DIM;
        if (L == 0){
            k_wprep<false><<<65, 256, 0, stream>>>(Wl, nullptr, wthi, wtlo, bias2);
            k_gemm<0><<<(N_NODES + 63)/64, 256, 0, stream>>>(x, wthi, wtlo,
                                                             bias2, hb);
        } else {
            k_wprep<true><<<65, 256, 0, stream>>>(Wl, scsh + (L-1)*256,
                                                  wthi, wtlo, bias2);
            k_gemm<1><<<(N_NODES + 63)/64, 256, 0, stream>>>(bufA, wthi, wtlo,
                                                             bias2, hb);
        }
        k_agg<<<2048, 256, 0, stream>>>(hb, rowptr, epair, dis, bs + L*DIM,
                                        bufA, stats + L*256);
        k_bnstat<<<1, 128, 0, stream>>>(stats + L*256, gs + L*DIM, be + L*DIM,
                                        scsh + L*256);
    }
    k_bn<<<3125, 256, 0, stream>>>((const uint4*)bufA, scsh + 3*256,
                                   (float4*)d_out);
}

// Round 13
// 566.124 us; speedup vs baseline: 1.1992x; 1.0487x over previous
//
#include <hip/hip_runtime.h>

#define N_NODES 50000
#define N_EDGES 800000
#define DIM 128
#define NLAYERS 4
#define BN_EPS 1e-5f
#define SCAN_BLOCKS 196   // ceil(N_NODES/256)
#define WS2 72            // 64 + 8 bf16 pad (k-half stride, bank decorrelation)

typedef __attribute__((ext_vector_type(8))) short short8;
typedef __attribute__((ext_vector_type(4))) float f32x4;

__device__ __forceinline__ float bf2f(unsigned short u){
    union { unsigned int i; float f; } x; x.i = ((unsigned int)u) << 16; return x.f;
}
__device__ __forceinline__ unsigned short f2bf(float f){
    union { float f; unsigned int i; } x; x.f = f;
    unsigned int lsb = (x.i >> 16) & 1u;
    unsigned int r = x.i + 0x7fffu + lsb;
    return (unsigned short)(r >> 16);
}

struct P4 { int2 a, b, c, d; };

__device__ __forceinline__ P4 loadP_mask(const int2* __restrict__ ep, int base,
                                         int sub, int lim){
    P4 p;
    int i0 = base + sub, i1 = base + 4 + sub, i2 = base + 8 + sub, i3 = base + 12 + sub;
    p.a = (i0 < lim) ? ep[i0] : make_int2(0, 0);
    p.b = (i1 < lim) ? ep[i1] : make_int2(0, 0);
    p.c = (i2 < lim) ? ep[i2] : make_int2(0, 0);
    p.d = (i3 < lim) ? ep[i3] : make_int2(0, 0);
    return p;
}
__device__ __forceinline__ P4 loadP_full(const int2* __restrict__ ep, int base,
                                         int sub){
    P4 p;
    p.a = ep[base + sub];
    p.b = ep[base + 4 + sub];
    p.c = ep[base + 8 + sub];
    p.d = ep[base + 12 + sub];
    return p;
}
__device__ __forceinline__ P4 loadP(const int2* __restrict__ ep, int base,
                                    int sub, int lim){
    if (lim - base >= 16) return loadP_full(ep, base, sub);
    return loadP_mask(ep, base, sub, lim);
}

// ---------------- prep kernels ----------------

__global__ __launch_bounds__(256) void k_zero(int* __restrict__ p, int n){
    int i = blockIdx.x * 256 + threadIdx.x;
    if (i < n) p[i] = 0;
}

__global__ __launch_bounds__(256) void k_count(const int* __restrict__ dst,
                                               int* __restrict__ degcnt){
    int e = blockIdx.x * 256 + threadIdx.x;
    if (e < N_EDGES) atomicAdd(&degcnt[dst[e]], 1);
}

// phase 1 + dis: per-block exclusive scan of degcnt; also dis = rsqrt(deg+1)
__global__ __launch_bounds__(256) void k_scan1(const int* __restrict__ degcnt,
                                               int* __restrict__ rowptr,
                                               int* __restrict__ bsum,
                                               float* __restrict__ dis){
    __shared__ int tmp[256];
    int t = threadIdx.x;
    int i = blockIdx.x * 256 + t;
    int v = (i < N_NODES) ? degcnt[i] : 0;
    if (i < N_NODES) dis[i] = rsqrtf((float)v + 1.0f);
    tmp[t] = v;
    __syncthreads();
    #pragma unroll
    for (int off = 1; off < 256; off <<= 1){
        int u = (t >= off) ? tmp[t - off] : 0;
        __syncthreads();
        tmp[t] += u;
        __syncthreads();
    }
    if (i < N_NODES) rowptr[i] = tmp[t] - v;
    if (t == 255) bsum[blockIdx.x] = tmp[255];
}

__global__ __launch_bounds__(256) void k_scan2(int* __restrict__ bsum){
    __shared__ int tmp[256];
    int t = threadIdx.x;
    int v = (t < SCAN_BLOCKS) ? bsum[t] : 0;
    tmp[t] = v;
    __syncthreads();
    #pragma unroll
    for (int off = 1; off < 256; off <<= 1){
        int u = (t >= off) ? tmp[t - off] : 0;
        __syncthreads();
        tmp[t] += u;
        __syncthreads();
    }
    if (t < SCAN_BLOCKS) bsum[t] = tmp[t] - v;
}

__global__ __launch_bounds__(256) void k_scan3(const int* __restrict__ bsum,
                                               int* __restrict__ rowptr,
                                               int* __restrict__ wptr){
    int i = blockIdx.x * 256 + threadIdx.x;
    if (i < N_NODES){
        int r = rowptr[i] + bsum[blockIdx.x];
        rowptr[i] = r; wptr[i] = r;
    }
    if (i == 0) rowptr[N_NODES] = N_EDGES;
}

__global__ __launch_bounds__(256) void k_fill(const int* __restrict__ src,
                                              const int* __restrict__ dst,
                                              const float* __restrict__ dis,
                                              int* __restrict__ wptr,
                                              int2* __restrict__ epair){
    int e = blockIdx.x * 256 + threadIdx.x;
    if (e < N_EDGES){
        int s = src[e], d = dst[e];
        float w = dis[s] * dis[d];
        int p = atomicAdd(&wptr[d], 1);
        int2 pr; pr.x = s; pr.y = __float_as_int(w);
        epair[p] = pr;
    }
}

// W' = diag(sc)*W; writes W'^T (c-major) bf16 hi/lo + bias2.
// sc/sh are computed IN-KERNEL from stats/gamma/beta (bnstat folded in).
template<bool HAS>
__global__ __launch_bounds__(256) void k_wprep(const float* __restrict__ W,
                                               const float* __restrict__ stats,
                                               const float* __restrict__ gamma,
                                               const float* __restrict__ beta,
                                               unsigned short* __restrict__ wthi,
                                               unsigned short* __restrict__ wtlo,
                                               float* __restrict__ bias2){
    int tid = threadIdx.x;
    if (blockIdx.x < 64){
        int idx = blockIdx.x * 256 + tid;        // 0..16383
        int c = idx >> 7, k = idx & 127;
        float v = W[k*DIM + c];
        if (HAS){
            float mu  = stats[k] * (1.0f / N_NODES);
            float var = stats[DIM + k] * (1.0f / N_NODES) - mu * mu;
            float sc  = rsqrtf(var + BN_EPS) * gamma[k];
            v *= sc;
        }
        unsigned short hi = f2bf(v);
        float lo = v - bf2f(hi);
        wthi[c*DIM + k] = hi;
        wtlo[c*DIM + k] = f2bf(lo);
    } else {
        __shared__ float part[256];
        int c = tid >> 1, half = tid & 1;
        float acc = 0.f;
        if (HAS){
            int k0 = half * 64;
            #pragma unroll 4
            for (int k = k0; k < k0 + 64; k++){
                float mu  = stats[k] * (1.0f / N_NODES);
                float var = stats[DIM + k] * (1.0f / N_NODES) - mu * mu;
                float sc  = rsqrtf(var + BN_EPS) * gamma[k];
                float sh  = beta[k] - mu * sc;
                acc = fmaf(sh, W[k*DIM + c], acc);
            }
        }
        part[tid] = acc;
        __syncthreads();
        if (half == 0) bias2[c] = part[2*c] + part[2*c + 1];
    }
}

// ---------------- per-layer kernels ----------------
// Grouped feature layout: t[g][node][32 cols], g = col>>5 (3.2MB/slice).

// MFMA GEMM: h = z @ W' + bias2. MODE 0: z = x fp32 std layout. MODE 1: z
// grouped bf16. W'^T staged in LDS in TWO k-halves (36.9KB -> 4 blocks/CU).
// 64 rows/block, 4 waves; wave = 16 rows x 128 cols = 8 mfma 16x16x32, K=128.
template<int MODE>
__global__ __launch_bounds__(256) void k_gemm(const void* __restrict__ zraw,
                                              const unsigned short* __restrict__ wthi,
                                              const unsigned short* __restrict__ wtlo,
                                              const float* __restrict__ bias2,
                                              unsigned short* __restrict__ hb){
    __shared__ short whi[DIM * WS2];           // 18432 B (k-half, all 128 cols)
    __shared__ short wlo[DIM * WS2];           // 18432 B
    int tid = threadIdx.x;

    int lane = tid & 63;
    int wv   = tid >> 6;
    int m = lane & 15;
    int q = lane >> 4;
    int row0 = blockIdx.x * 64 + wv * 16;
    int arow = row0 + m;
    bool avalid = arow < N_NODES;

    f32x4 acc[8];
    #pragma unroll
    for (int t = 0; t < 8; t++) acc[t] = (f32x4){0.f, 0.f, 0.f, 0.f};

    const uint4* gh = (const uint4*)wthi;      // row c = 16 uint4 (128 shorts)
    const uint4* gl = (const uint4*)wtlo;

    #pragma unroll
    for (int half = 0; half < 2; half++){
        // stage k-half: whi[c][72], valid offs 0..63 = global k half*64+off
        #pragma unroll
        for (int it = 0; it < 4; it++){
            int ch = tid + 256*it;             // 0..1023 uint4 chunks
            int c = ch >> 3, k8 = ch & 7;      // 8 uint4 per 64-short row
            int off = c*WS2 + k8*8;
            int srci = c*16 + half*8 + k8;
            *(uint4*)&whi[off] = gh[srci];
            *(uint4*)&wlo[off] = gl[srci];
        }
        __syncthreads();

        #pragma unroll
        for (int gl2 = 0; gl2 < 2; gl2++){     // local group within half
            int gg = half*2 + gl2;             // global feature group
            short8 a = {0,0,0,0,0,0,0,0};
            if (avalid){
                if (MODE == 0){
                    const float* xp = (const float*)zraw + (size_t)arow*DIM + gg*32 + q*8;
                    float4 v0 = *(const float4*)xp;
                    float4 v1 = *(const float4*)(xp + 4);
                    a[0] = (short)f2bf(v0.x); a[1] = (short)f2bf(v0.y);
                    a[2] = (short)f2bf(v0.z); a[3] = (short)f2bf(v0.w);
                    a[4] = (short)f2bf(v1.x); a[5] = (short)f2bf(v1.y);
                    a[6] = (short)f2bf(v1.z); a[7] = (short)f2bf(v1.w);
                } else {
                    a = *(const short8*)((const unsigned short*)zraw
                          + (size_t)gg*N_NODES*32 + (size_t)arow*32 + q*8);
                }
            }
            #pragma unroll
            for (int t = 0; t < 8; t++){
                int col = t*16 + m;
                int off = col*WS2 + gl2*32 + q*8;
                short8 bh = *(const short8*)&whi[off];
                short8 bl = *(const short8*)&wlo[off];
                acc[t] = __builtin_amdgcn_mfma_f32_16x16x32_bf16(a, bh, acc[t], 0, 0, 0);
                acc[t] = __builtin_amdgcn_mfma_f32_16x16x32_bf16(a, bl, acc[t], 0, 0, 0);
            }
        }
        if (half == 0) __syncthreads();        // drain reads before restage
    }

    #pragma unroll
    for (int t = 0; t < 8; t++){
        int colg = t*16 + m;
        float bz = bias2[colg];
        size_t base = (size_t)(t >> 1)*N_NODES*32 + (t & 1)*16 + m;
        #pragma unroll
        for (int r = 0; r < 4; r++){
            int row = row0 + q*4 + r;
            if (row < N_NODES)
                hb[base + (size_t)row*32] = f2bf(acc[t][r] + bz);
        }
    }
}

// CSR aggregation + bias + ReLU + per-column stats, feature-group partitioned.
// group = blockIdx&3. 16 lanes/edge (ushort2), masked/full 16-edge chunks with
// epair pipelining and next-node header prefetch.
__global__ __launch_bounds__(256) void k_agg(const unsigned short* __restrict__ h,
                                             const int* __restrict__ rowptr,
                                             const int2* __restrict__ epair,
                                             const float* __restrict__ dis,
                                             const float* __restrict__ bias,
                                             unsigned short* __restrict__ out,
                                             float* __restrict__ stats){
    int lane = threadIdx.x & 63;
    int w    = threadIdx.x >> 6;
    int g    = blockIdx.x & 3;
    int sub  = lane >> 4;
    int cp   = lane & 15;
    const ushort2* hg = (const ushort2*)(h + (size_t)g * N_NODES * 32);
    ushort2* og = (ushort2*)(out + (size_t)g * N_NODES * 32);
    float b0 = bias[g*32 + 2*cp], b1 = bias[g*32 + 2*cp + 1];
    float s0 = 0.f, s1 = 0.f, q0 = 0.f, q1 = 0.f;
    int bg = blockIdx.x >> 2;
    int nstride = (gridDim.x >> 2) * 4;

    int node = bg*4 + w;
    int ne0 = 0, ne1 = 0;
    ushort2 nhv; nhv.x = 0; nhv.y = 0;
    float ndi = 0.f;
    P4 nP = {{0,0},{0,0},{0,0},{0,0}};
    if (node < N_NODES){
        ne0 = rowptr[node];
        ne1 = rowptr[node + 1];
        nhv = hg[node*16 + cp];
        ndi = dis[node];
        nP  = loadP(epair, ne0, sub, ne1);
    }

    while (node < N_NODES){
        int e0 = ne0, e1 = ne1;
        ushort2 hv = nhv;
        float di = ndi;
        P4 P = nP;

        int nnext = node + nstride;
        if (nnext < N_NODES){                  // prefetch next node header
            ne0 = rowptr[nnext];
            ne1 = rowptr[nnext + 1];
            nhv = hg[nnext*16 + cp];
            ndi = dis[nnext];
        } else { ne0 = 0; ne1 = 0; }

        float pa0 = 0.f, pa1 = 0.f, pb0 = 0.f, pb1 = 0.f;
        float pc0 = 0.f, pc1 = 0.f, pd0 = 0.f, pd1 = 0.f;
        if (sub == 0){
            float dii = di * di;
            pa0 = bf2f(hv.x) * dii; pa1 = bf2f(hv.y) * dii;
        }

        int e = e0;
        while (e < e1){
            int en = e + 16;
            P4 Pn = {{0,0},{0,0},{0,0},{0,0}};
            if (en < e1) Pn = loadP(epair, en, sub, e1);   // pipeline epairs
            ushort2 X0 = hg[P.a.x*16 + cp];
            ushort2 X1 = hg[P.b.x*16 + cp];
            ushort2 X2 = hg[P.c.x*16 + cp];
            ushort2 X3 = hg[P.d.x*16 + cp];
            float w0 = __int_as_float(P.a.y), w1 = __int_as_float(P.b.y);
            float w2 = __int_as_float(P.c.y), w3 = __int_as_float(P.d.y);
            pa0 = fmaf(bf2f(X0.x), w0, pa0); pa1 = fmaf(bf2f(X0.y), w0, pa1);
            pb0 = fmaf(bf2f(X1.x), w1, pb0); pb1 = fmaf(bf2f(X1.y), w1, pb1);
            pc0 = fmaf(bf2f(X2.x), w2, pc0); pc1 = fmaf(bf2f(X2.y), w2, pc1);
            pd0 = fmaf(bf2f(X3.x), w3, pd0); pd1 = fmaf(bf2f(X3.y), w3, pd1);
            P = Pn;
            e = en;
        }

        float r0 = (pa0 + pb0) + (pc0 + pd0);
        float r1 = (pa1 + pb1) + (pc1 + pd1);
        r0 += __shfl_xor(r0, 16); r1 += __shfl_xor(r1, 16);
        r0 += __shfl_xor(r0, 32); r1 += __shfl_xor(r1, 32);
        if (sub == 0){
            float a0 = fmaxf(r0 + b0, 0.f);
            float a1 = fmaxf(r1 + b1, 0.f);
            ushort2 ov; ov.x = f2bf(a0); ov.y = f2bf(a1);
            og[node*16 + cp] = ov;
            s0 += a0; s1 += a1; q0 += a0*a0; q1 += a1*a1;
        }

        if (nnext < N_NODES)                   // prefetch next node's chunk 0
            nP = loadP(epair, ne0, sub, ne1);
        node = nnext;
    }

    __shared__ float red[4][16][4];
    if (sub == 0){
        red[w][cp][0] = s0; red[w][cp][1] = s1;
        red[w][cp][2] = q0; red[w][cp][3] = q1;
    }
    __syncthreads();
    if (w == 0 && sub == 0){
        #pragma unroll
        for (int ww = 1; ww < 4; ww++){
            s0 += red[ww][cp][0]; s1 += red[ww][cp][1];
            q0 += red[ww][cp][2]; q1 += red[ww][cp][3];
        }
        int c = g*32 + 2*cp;
        atomicAdd(&stats[c],         s0);
        atomicAdd(&stats[c + 1],     s1);
        atomicAdd(&stats[DIM + c],     q0);
        atomicAdd(&stats[DIM + c + 1], q1);
    }
}

// final-layer BN apply: grouped bf16 in -> standard-layout fp32 out.
// scsh computed in-kernel from stats/gamma/beta (bnstat folded in).
__global__ __launch_bounds__(256) void k_bn(const uint4* __restrict__ in,
                                            const float* __restrict__ stats,
                                            const float* __restrict__ gamma,
                                            const float* __restrict__ beta,
                                            float4* __restrict__ outf){
    __shared__ float scs[DIM], shs[DIM];
    int tid = threadIdx.x;
    if (tid < DIM){
        float mu  = stats[tid] * (1.0f / N_NODES);
        float var = stats[DIM + tid] * (1.0f / N_NODES) - mu * mu;
        float sc  = rsqrtf(var + BN_EPS) * gamma[tid];
        scs[tid] = sc;
        shs[tid] = beta[tid] - mu * sc;
    }
    __syncthreads();

    int i = blockIdx.x * 256 + tid;                 // 8-bf16 chunk index
    if (i >= N_NODES * DIM / 8) return;
    int row = i >> 4;
    int c = (i * 8) & (DIM - 1);
    int gg = c >> 5, wi = c & 31;
    uint4 raw = in[gg*(N_NODES*4) + row*4 + (wi >> 3)];
    unsigned int u[4] = {raw.x, raw.y, raw.z, raw.w};
    float v[8];
    #pragma unroll
    for (int j = 0; j < 4; j++){
        v[2*j]   = bf2f((unsigned short)(u[j] & 0xffff));
        v[2*j+1] = bf2f((unsigned short)(u[j] >> 16));
    }
    float4 r0, r1;
    r0.x = fmaf(v[0], scs[c+0], shs[c+0]);
    r0.y = fmaf(v[1], scs[c+1], shs[c+1]);
    r0.z = fmaf(v[2], scs[c+2], shs[c+2]);
    r0.w = fmaf(v[3], scs[c+3], shs[c+3]);
    r1.x = fmaf(v[4], scs[c+4], shs[c+4]);
    r1.y = fmaf(v[5], scs[c+5], shs[c+5]);
    r1.z = fmaf(v[6], scs[c+6], shs[c+6]);
    r1.w = fmaf(v[7], scs[c+7], shs[c+7]);
    outf[2*i]   = r0;
    outf[2*i+1] = r1;
}

// ---------------- launch ----------------

extern "C" void kernel_launch(void* const* d_in, const int* in_sizes, int n_in,
                              void* d_out, int out_size, void* d_ws, size_t ws_size,
                              hipStream_t stream){
    const float* x   = (const float*)d_in[0];
    const int*   src = (const int*)d_in[1];
    const int*   dst = src + N_EDGES;
    const float* Ws  = (const float*)d_in[2];
    const float* bs  = (const float*)d_in[3];
    const float* gs  = (const float*)d_in[4];
    const float* be  = (const float*)d_in[5];

    char* w = (char*)d_ws;
    int*   degcnt = (int*)(w);                         // 50000 i  [0,200000)
    float* stats  = (float*)(w + 200000);              // 1024 f
    float* dis    = (float*)(w + 208192);              // 50000 f
    int*   rowptr = (int*)(w + 408192);                // 50001 i (pad)
    int*   wptr   = (int*)(w + 608208);                // 50000 i
    int*   bsum   = (int*)(w + 808208);                // 196 i (pad)
    float* bias2  = (float*)(w + 809232);              // 128 f
    unsigned short* wthi = (unsigned short*)(w + 809744);   // 16384 bf16
    unsigned short* wtlo = (unsigned short*)(w + 842512);   // 16384 bf16
    int2*  epair  = (int2*)(w + 875280);               // 800000 int2 (6.4MB)
    unsigned short* bufA = (unsigned short*)(w + 7275280);   // grouped bf16 (12.8MB)
    unsigned short* hb   = (unsigned short*)(w + 20075280);  // grouped bf16 (12.8MB)
    // total: 32,875,280 bytes

    k_zero<<<(51024 + 255)/256, 256, 0, stream>>>(degcnt, 51024);
    k_count<<<3125, 256, 0, stream>>>(dst, degcnt);
    k_scan1<<<SCAN_BLOCKS, 256, 0, stream>>>(degcnt, rowptr, bsum, dis);
    k_scan2<<<1, 256, 0, stream>>>(bsum);
    k_scan3<<<SCAN_BLOCKS, 256, 0, stream>>>(bsum, rowptr, wptr);
    k_fill<<<3125, 256, 0, stream>>>(src, dst, dis, wptr, epair);

    for (int L = 0; L < NLAYERS; L++){
        const float* Wl = Ws + L*DIM*DIM;
        if (L == 0){
            k_wprep<false><<<65, 256, 0, stream>>>(Wl, nullptr, nullptr, nullptr,
                                                   wthi, wtlo, bias2);
            k_gemm<0><<<(N_NODES + 63)/64, 256, 0, stream>>>(x, wthi, wtlo,
                                                             bias2, hb);
        } else {
            k_wprep<true><<<65, 256, 0, stream>>>(Wl, stats + (L-1)*256,
                                                  gs + (L-1)*DIM, be + (L-1)*DIM,
                                                  wthi, wtlo, bias2);
            k_gemm<1><<<(N_NODES + 63)/64, 256, 0, stream>>>(bufA, wthi, wtlo,
                                                             bias2, hb);
        }
        k_agg<<<2048, 256, 0, stream>>>(hb, rowptr, epair, dis, bs + L*DIM,
                                        bufA, stats + L*256);
    }
    k_bn<<<3125, 256, 0, stream>>>((const uint4*)bufA, stats + 3*256,
                                   gs + 3*DIM, be + 3*DIM, (float4*)d_out);
}

// Round 14
// 552.828 us; speedup vs baseline: 1.2281x; 1.0241x over previous
//
#include <hip/hip_runtime.h>

#define N_NODES 50000
#define N_EDGES 800000
#define DIM 128
#define NLAYERS 4
#define BN_EPS 1e-5f
#define SCAN_BLOCKS 196   // ceil(N_NODES/256)
#define WS2 72            // 64 + 8 bf16 pad (k-half stride, bank decorrelation)

typedef __attribute__((ext_vector_type(8))) short short8;
typedef __attribute__((ext_vector_type(4))) float f32x4;

__device__ __forceinline__ float bf2f(unsigned short u){
    union { unsigned int i; float f; } x; x.i = ((unsigned int)u) << 16; return x.f;
}
__device__ __forceinline__ unsigned short f2bf(float f){
    union { float f; unsigned int i; } x; x.f = f;
    unsigned int lsb = (x.i >> 16) & 1u;
    unsigned int r = x.i + 0x7fffu + lsb;
    return (unsigned short)(r >> 16);
}

struct P4 { int2 a, b, c, d; };

__device__ __forceinline__ P4 loadP_mask(const int2* __restrict__ ep, int base,
                                         int sub, int lim){
    P4 p;
    int i0 = base + sub, i1 = base + 4 + sub, i2 = base + 8 + sub, i3 = base + 12 + sub;
    p.a = (i0 < lim) ? ep[i0] : make_int2(0, 0);
    p.b = (i1 < lim) ? ep[i1] : make_int2(0, 0);
    p.c = (i2 < lim) ? ep[i2] : make_int2(0, 0);
    p.d = (i3 < lim) ? ep[i3] : make_int2(0, 0);
    return p;
}
__device__ __forceinline__ P4 loadP_full(const int2* __restrict__ ep, int base,
                                         int sub){
    P4 p;
    p.a = ep[base + sub];
    p.b = ep[base + 4 + sub];
    p.c = ep[base + 8 + sub];
    p.d = ep[base + 12 + sub];
    return p;
}
__device__ __forceinline__ P4 loadP(const int2* __restrict__ ep, int base,
                                    int sub, int lim){
    if (lim - base >= 16) return loadP_full(ep, base, sub);
    return loadP_mask(ep, base, sub, lim);
}

// ---------------- prep kernels ----------------

__global__ __launch_bounds__(256) void k_zero(int* __restrict__ p, int n){
    int i = blockIdx.x * 256 + threadIdx.x;
    if (i < n) p[i] = 0;
}

__global__ __launch_bounds__(256) void k_count(const int* __restrict__ dst,
                                               int* __restrict__ degcnt){
    int e = blockIdx.x * 256 + threadIdx.x;
    if (e < N_EDGES) atomicAdd(&degcnt[dst[e]], 1);
}

// phase 1 + dis: per-block exclusive scan of degcnt; also dis = rsqrt(deg+1)
__global__ __launch_bounds__(256) void k_scan1(const int* __restrict__ degcnt,
                                               int* __restrict__ rowptr,
                                               int* __restrict__ bsum,
                                               float* __restrict__ dis){
    __shared__ int tmp[256];
    int t = threadIdx.x;
    int i = blockIdx.x * 256 + t;
    int v = (i < N_NODES) ? degcnt[i] : 0;
    if (i < N_NODES) dis[i] = rsqrtf((float)v + 1.0f);
    tmp[t] = v;
    __syncthreads();
    #pragma unroll
    for (int off = 1; off < 256; off <<= 1){
        int u = (t >= off) ? tmp[t - off] : 0;
        __syncthreads();
        tmp[t] += u;
        __syncthreads();
    }
    if (i < N_NODES) rowptr[i] = tmp[t] - v;
    if (t == 255) bsum[blockIdx.x] = tmp[255];
}

// scan3 with scan2 folded in: each block scans bsum itself and applies offset
__global__ __launch_bounds__(256) void k_scan3(const int* __restrict__ bsum,
                                               int* __restrict__ rowptr,
                                               int* __restrict__ wptr){
    __shared__ int tmp[256];
    int t = threadIdx.x;
    int v = (t < SCAN_BLOCKS) ? bsum[t] : 0;
    tmp[t] = v;
    __syncthreads();
    #pragma unroll
    for (int off = 1; off < 256; off <<= 1){
        int u = (t >= off) ? tmp[t - off] : 0;
        __syncthreads();
        tmp[t] += u;
        __syncthreads();
    }
    int boff = (blockIdx.x == 0) ? 0 : tmp[blockIdx.x - 1];  // exclusive
    int i = blockIdx.x * 256 + t;
    if (i < N_NODES){
        int r = rowptr[i] + boff;
        rowptr[i] = r; wptr[i] = r;
    }
    if (i == 0) rowptr[N_NODES] = N_EDGES;
}

__global__ __launch_bounds__(256) void k_fill(const int* __restrict__ src,
                                              const int* __restrict__ dst,
                                              const float* __restrict__ dis,
                                              int* __restrict__ wptr,
                                              int2* __restrict__ epair){
    int e = blockIdx.x * 256 + threadIdx.x;
    if (e < N_EDGES){
        int s = src[e], d = dst[e];
        float w = dis[s] * dis[d];
        int p = atomicAdd(&wptr[d], 1);
        int2 pr; pr.x = s; pr.y = __float_as_int(w);
        epair[p] = pr;
    }
}

// ---------------- per-layer kernels ----------------
// Grouped feature layout: t[g][node][32 cols], g = col>>5 (3.2MB/slice).

// MFMA GEMM with W-prep fully folded in:
//   h = (z*sc + sh) @ W + b2  computed as  z @ (diag(sc)W) + (sh@W)
// MODE 0: z = x fp32 std layout, sc=1 sh=0. MODE 1: z grouped bf16, sc/sh
// derived in-kernel from stats/gamma/beta. W (fp32, global) is staged per
// k-half as bf16 hi/lo into LDS (36.9KB -> 4 blocks/CU).
// 64 rows/block, 4 waves; wave = 16 rows x 128 cols = 8 mfma 16x16x32, K=128.
template<int MODE>
__global__ __launch_bounds__(256) void k_gemm(const void* __restrict__ zraw,
                                              const float* __restrict__ W,
                                              const float* __restrict__ stats,
                                              const float* __restrict__ gamma,
                                              const float* __restrict__ beta,
                                              unsigned short* __restrict__ hb){
    __shared__ short whi[DIM * WS2];           // 18432 B (k-half, all 128 cols)
    __shared__ short wlo[DIM * WS2];           // 18432 B
    __shared__ float scs[DIM], shs[DIM];       // BN fold factors
    __shared__ float part[256];                // bias2 partials
    __shared__ float b2[DIM];                  // bias2
    int tid = threadIdx.x;

    if (MODE == 1){
        if (tid < DIM){
            float mu  = stats[tid] * (1.0f / N_NODES);
            float var = stats[DIM + tid] * (1.0f / N_NODES) - mu * mu;
            float sc  = rsqrtf(var + BN_EPS) * gamma[tid];
            scs[tid] = sc;
            shs[tid] = beta[tid] - mu * sc;
        }
        __syncthreads();
        // bias2 partials: 2 threads per col, 64 k each
        {
            int c = tid >> 1, half = tid & 1;
            float acc = 0.f;
            int k0 = half * 64;
            #pragma unroll 4
            for (int k = k0; k < k0 + 64; k++)
                acc = fmaf(shs[k], W[k*DIM + c], acc);
            part[tid] = acc;
        }
    } else {
        if (tid < DIM) b2[tid] = 0.f;
    }

    int lane = tid & 63;
    int wv   = tid >> 6;
    int m = lane & 15;
    int q = lane >> 4;
    int row0 = blockIdx.x * 64 + wv * 16;
    int arow = row0 + m;
    bool avalid = arow < N_NODES;

    f32x4 acc[8];
    #pragma unroll
    for (int t = 0; t < 8; t++) acc[t] = (f32x4){0.f, 0.f, 0.f, 0.f};

    #pragma unroll
    for (int half = 0; half < 2; half++){
        // stage k-half of diag(sc)*W as hi/lo bf16, transposed: whi[c][k]
        // chunk ch in [0,1024): kc = ch>>7 (0..7), c = ch&127. coalesced reads.
        #pragma unroll
        for (int it = 0; it < 4; it++){
            int ch = tid + 256*it;
            int kc = ch >> 7, c = ch & 127;
            int kbase = half*64 + kc*8;
            short8 vh, vl;
            #pragma unroll
            for (int i = 0; i < 8; i++){
                float v = W[(kbase + i)*DIM + c];
                if (MODE == 1) v *= scs[kbase + i];
                unsigned short h = f2bf(v);
                float lo = v - bf2f(h);
                vh[i] = (short)h;
                vl[i] = (short)f2bf(lo);
            }
            *(short8*)&whi[c*WS2 + kc*8] = vh;
            *(short8*)&wlo[c*WS2 + kc*8] = vl;
        }
        __syncthreads();
        if (MODE == 1 && half == 0){
            if (tid < DIM) b2[tid] = part[2*tid] + part[2*tid + 1];
        }

        #pragma unroll
        for (int gl2 = 0; gl2 < 2; gl2++){     // local group within half
            int gg = half*2 + gl2;             // global feature group
            short8 a = {0,0,0,0,0,0,0,0};
            if (avalid){
                if (MODE == 0){
                    const float* xp = (const float*)zraw + (size_t)arow*DIM + gg*32 + q*8;
                    float4 v0 = *(const float4*)xp;
                    float4 v1 = *(const float4*)(xp + 4);
                    a[0] = (short)f2bf(v0.x); a[1] = (short)f2bf(v0.y);
                    a[2] = (short)f2bf(v0.z); a[3] = (short)f2bf(v0.w);
                    a[4] = (short)f2bf(v1.x); a[5] = (short)f2bf(v1.y);
                    a[6] = (short)f2bf(v1.z); a[7] = (short)f2bf(v1.w);
                } else {
                    a = *(const short8*)((const unsigned short*)zraw
                          + (size_t)gg*N_NODES*32 + (size_t)arow*32 + q*8);
                }
            }
            #pragma unroll
            for (int t = 0; t < 8; t++){
                int col = t*16 + m;
                int off = col*WS2 + gl2*32 + q*8;
                short8 bh = *(const short8*)&whi[off];
                short8 bl = *(const short8*)&wlo[off];
                acc[t] = __builtin_amdgcn_mfma_f32_16x16x32_bf16(a, bh, acc[t], 0, 0, 0);
                acc[t] = __builtin_amdgcn_mfma_f32_16x16x32_bf16(a, bl, acc[t], 0, 0, 0);
            }
        }
        if (half == 0) __syncthreads();        // drain reads before restage
    }

    #pragma unroll
    for (int t = 0; t < 8; t++){
        int colg = t*16 + m;
        float bz = b2[colg];
        size_t base = (size_t)(t >> 1)*N_NODES*32 + (t & 1)*16 + m;
        #pragma unroll
        for (int r = 0; r < 4; r++){
            int row = row0 + q*4 + r;
            if (row < N_NODES)
                hb[base + (size_t)row*32] = f2bf(acc[t][r] + bz);
        }
    }
}

// CSR aggregation + bias + ReLU + per-column stats, feature-group partitioned.
// group = blockIdx&3. 16 lanes/edge (ushort2), masked/full 16-edge chunks with
// epair pipelining and next-node header prefetch.
__global__ __launch_bounds__(256) void k_agg(const unsigned short* __restrict__ h,
                                             const int* __restrict__ rowptr,
                                             const int2* __restrict__ epair,
                                             const float* __restrict__ dis,
                                             const float* __restrict__ bias,
                                             unsigned short* __restrict__ out,
                                             float* __restrict__ stats){
    int lane = threadIdx.x & 63;
    int w    = threadIdx.x >> 6;
    int g    = blockIdx.x & 3;
    int sub  = lane >> 4;
    int cp   = lane & 15;
    const ushort2* hg = (const ushort2*)(h + (size_t)g * N_NODES * 32);
    ushort2* og = (ushort2*)(out + (size_t)g * N_NODES * 32);
    float b0 = bias[g*32 + 2*cp], b1 = bias[g*32 + 2*cp + 1];
    float s0 = 0.f, s1 = 0.f, q0 = 0.f, q1 = 0.f;
    int bg = blockIdx.x >> 2;
    int nstride = (gridDim.x >> 2) * 4;

    int node = bg*4 + w;
    int ne0 = 0, ne1 = 0;
    ushort2 nhv; nhv.x = 0; nhv.y = 0;
    float ndi = 0.f;
    P4 nP = {{0,0},{0,0},{0,0},{0,0}};
    if (node < N_NODES){
        ne0 = rowptr[node];
        ne1 = rowptr[node + 1];
        nhv = hg[node*16 + cp];
        ndi = dis[node];
        nP  = loadP(epair, ne0, sub, ne1);
    }

    while (node < N_NODES){
        int e0 = ne0, e1 = ne1;
        ushort2 hv = nhv;
        float di = ndi;
        P4 P = nP;

        int nnext = node + nstride;
        if (nnext < N_NODES){                  // prefetch next node header
            ne0 = rowptr[nnext];
            ne1 = rowptr[nnext + 1];
            nhv = hg[nnext*16 + cp];
            ndi = dis[nnext];
        } else { ne0 = 0; ne1 = 0; }

        float pa0 = 0.f, pa1 = 0.f, pb0 = 0.f, pb1 = 0.f;
        float pc0 = 0.f, pc1 = 0.f, pd0 = 0.f, pd1 = 0.f;
        if (sub == 0){
            float dii = di * di;
            pa0 = bf2f(hv.x) * dii; pa1 = bf2f(hv.y) * dii;
        }

        int e = e0;
        while (e < e1){
            int en = e + 16;
            P4 Pn = {{0,0},{0,0},{0,0},{0,0}};
            if (en < e1) Pn = loadP(epair, en, sub, e1);   // pipeline epairs
            ushort2 X0 = hg[P.a.x*16 + cp];
            ushort2 X1 = hg[P.b.x*16 + cp];
            ushort2 X2 = hg[P.c.x*16 + cp];
            ushort2 X3 = hg[P.d.x*16 + cp];
            float w0 = __int_as_float(P.a.y), w1 = __int_as_float(P.b.y);
            float w2 = __int_as_float(P.c.y), w3 = __int_as_float(P.d.y);
            pa0 = fmaf(bf2f(X0.x), w0, pa0); pa1 = fmaf(bf2f(X0.y), w0, pa1);
            pb0 = fmaf(bf2f(X1.x), w1, pb0); pb1 = fmaf(bf2f(X1.y), w1, pb1);
            pc0 = fmaf(bf2f(X2.x), w2, pc0); pc1 = fmaf(bf2f(X2.y), w2, pc1);
            pd0 = fmaf(bf2f(X3.x), w3, pd0); pd1 = fmaf(bf2f(X3.y), w3, pd1);
            P = Pn;
            e = en;
        }

        float r0 = (pa0 + pb0) + (pc0 + pd0);
        float r1 = (pa1 + pb1) + (pc1 + pd1);
        r0 += __shfl_xor(r0, 16); r1 += __shfl_xor(r1, 16);
        r0 += __shfl_xor(r0, 32); r1 += __shfl_xor(r1, 32);
        if (sub == 0){
            float a0 = fmaxf(r0 + b0, 0.f);
            float a1 = fmaxf(r1 + b1, 0.f);
            ushort2 ov; ov.x = f2bf(a0); ov.y = f2bf(a1);
            og[node*16 + cp] = ov;
            s0 += a0; s1 += a1; q0 += a0*a0; q1 += a1*a1;
        }

        if (nnext < N_NODES)                   // prefetch next node's chunk 0
            nP = loadP(epair, ne0, sub, ne1);
        node = nnext;
    }

    __shared__ float red[4][16][4];
    if (sub == 0){
        red[w][cp][0] = s0; red[w][cp][1] = s1;
        red[w][cp][2] = q0; red[w][cp][3] = q1;
    }
    __syncthreads();
    if (w == 0 && sub == 0){
        #pragma unroll
        for (int ww = 1; ww < 4; ww++){
            s0 += red[ww][cp][0]; s1 += red[ww][cp][1];
            q0 += red[ww][cp][2]; q1 += red[ww][cp][3];
        }
        int c = g*32 + 2*cp;
        atomicAdd(&stats[c],         s0);
        atomicAdd(&stats[c + 1],     s1);
        atomicAdd(&stats[DIM + c],     q0);
        atomicAdd(&stats[DIM + c + 1], q1);
    }
}

// final-layer BN apply: grouped bf16 in -> standard-layout fp32 out.
// scsh computed in-kernel from stats/gamma/beta.
__global__ __launch_bounds__(256) void k_bn(const uint4* __restrict__ in,
                                            const float* __restrict__ stats,
                                            const float* __restrict__ gamma,
                                            const float* __restrict__ beta,
                                            float4* __restrict__ outf){
    __shared__ float scs[DIM], shs[DIM];
    int tid = threadIdx.x;
    if (tid < DIM){
        float mu  = stats[tid] * (1.0f / N_NODES);
        float var = stats[DIM + tid] * (1.0f / N_NODES) - mu * mu;
        float sc  = rsqrtf(var + BN_EPS) * gamma[tid];
        scs[tid] = sc;
        shs[tid] = beta[tid] - mu * sc;
    }
    __syncthreads();

    int i = blockIdx.x * 256 + tid;                 // 8-bf16 chunk index
    if (i >= N_NODES * DIM / 8) return;
    int row = i >> 4;
    int c = (i * 8) & (DIM - 1);
    int gg = c >> 5, wi = c & 31;
    uint4 raw = in[gg*(N_NODES*4) + row*4 + (wi >> 3)];
    unsigned int u[4] = {raw.x, raw.y, raw.z, raw.w};
    float v[8];
    #pragma unroll
    for (int j = 0; j < 4; j++){
        v[2*j]   = bf2f((unsigned short)(u[j] & 0xffff));
        v[2*j+1] = bf2f((unsigned short)(u[j] >> 16));
    }
    float4 r0, r1;
    r0.x = fmaf(v[0], scs[c+0], shs[c+0]);
    r0.y = fmaf(v[1], scs[c+1], shs[c+1]);
    r0.z = fmaf(v[2], scs[c+2], shs[c+2]);
    r0.w = fmaf(v[3], scs[c+3], shs[c+3]);
    r1.x = fmaf(v[4], scs[c+4], shs[c+4]);
    r1.y = fmaf(v[5], scs[c+5], shs[c+5]);
    r1.z = fmaf(v[6], scs[c+6], shs[c+6]);
    r1.w = fmaf(v[7], scs[c+7], shs[c+7]);
    outf[2*i]   = r0;
    outf[2*i+1] = r1;
}

// ---------------- launch ----------------

extern "C" void kernel_launch(void* const* d_in, const int* in_sizes, int n_in,
                              void* d_out, int out_size, void* d_ws, size_t ws_size,
                              hipStream_t stream){
    const float* x   = (const float*)d_in[0];
    const int*   src = (const int*)d_in[1];
    const int*   dst = src + N_EDGES;
    const float* Ws  = (const float*)d_in[2];
    const float* bs  = (const float*)d_in[3];
    const float* gs  = (const float*)d_in[4];
    const float* be  = (const float*)d_in[5];

    char* w = (char*)d_ws;
    int*   degcnt = (int*)(w);                         // 50000 i  [0,200000)
    float* stats  = (float*)(w + 200000);              // 1024 f
    float* dis    = (float*)(w + 208192);              // 50000 f
    int*   rowptr = (int*)(w + 408192);                // 50001 i (pad)
    int*   wptr   = (int*)(w + 608208);                // 50000 i
    int*   bsum   = (int*)(w + 808208);                // 196 i (pad)
    int2*  epair  = (int2*)(w + 875280);               // 800000 int2 (6.4MB)
    unsigned short* bufA = (unsigned short*)(w + 7275280);   // grouped bf16 (12.8MB)
    unsigned short* hb   = (unsigned short*)(w + 20075280);  // grouped bf16 (12.8MB)
    // total: 32,875,280 bytes

    k_zero<<<(51024 + 255)/256, 256, 0, stream>>>(degcnt, 51024);
    k_count<<<3125, 256, 0, stream>>>(dst, degcnt);
    k_scan1<<<SCAN_BLOCKS, 256, 0, stream>>>(degcnt, rowptr, bsum, dis);
    k_scan3<<<SCAN_BLOCKS, 256, 0, stream>>>(bsum, rowptr, wptr);
    k_fill<<<3125, 256, 0, stream>>>(src, dst, dis, wptr, epair);

    for (int L = 0; L < NLAYERS; L++){
        const float* Wl = Ws + L*DIM*DIM;
        if (L == 0)
            k_gemm<0><<<(N_NODES + 63)/64, 256, 0, stream>>>(x, Wl,
                    nullptr, nullptr, nullptr, hb);
        else
            k_gemm<1><<<(N_NODES + 63)/64, 256, 0, stream>>>(bufA, Wl,
                    stats + (L-1)*256, gs + (L-1)*DIM, be + (L-1)*DIM, hb);
        k_agg<<<2048, 256, 0, stream>>>(hb, rowptr, epair, dis, bs + L*DIM,
                                        bufA, stats + L*256);
    }
    k_bn<<<3125, 256, 0, stream>>>((const uint4*)bufA, stats + 3*256,
                                   gs + 3*DIM, be + 3*DIM, (float4*)d_out);
}